// Round 12
// baseline (199.080 us; speedup 1.0000x reference)
//
#include <hip/hip_runtime.h>

#define N_NODES 100000
#define N_EDGES 1600000
#define D 64
#define NUM_GRAPHS 64
#define EPS 1e-5f

// ---- bucketed CSR build params ----
#define BSHIFT 9
#define NPB 512
#define NBUCKETS ((N_NODES + NPB - 1) / NPB)      // 196
#define BCAP 12288                                 // fixed bucket capacity
#define A_THREADS 1024
#define A_EPT 8
#define A_CHUNK (A_THREADS * A_EPT)               // 8192
#define NBLK_A ((N_EDGES + A_CHUNK - 1) / A_CHUNK) // 196
#define XB ((N_NODES * 64 / 8 + 255) / 256)       // xcast blocks (3125)

// ---- legacy scan params (fallback path) ----
#define SCAN_T 256
#define SCAN_E 8
#define SCAN_CHUNK (SCAN_T * SCAN_E)
#define NSCAN ((N_NODES + SCAN_CHUNK - 1) / SCAN_CHUNK)

typedef float f32x4 __attribute__((ext_vector_type(4)));
typedef short bf16x8 __attribute__((ext_vector_type(8)));

__device__ __forceinline__ ushort f32_to_bf16_rne(float v) {
    unsigned int bits = __float_as_uint(v);
    return (ushort)((bits + 0x7FFFu + ((bits >> 16) & 1u)) >> 16);
}

// ===========================================================================
// fused: blocks [0,XB) cast x->bf16; blocks [XB,XB+16) init cursors + stats
// ===========================================================================
__global__ __launch_bounds__(256) void xcast_init_kernel(
    const float* __restrict__ x, ushort* __restrict__ xh,
    int* __restrict__ bucket_cur, float* __restrict__ gsum,
    float* __restrict__ gsum2, float* __restrict__ gcnt)
{
    if (blockIdx.x < XB) {
        int i = blockIdx.x * blockDim.x + threadIdx.x;
        if (i >= N_NODES * 64 / 8) return;
        const float4* src = reinterpret_cast<const float4*>(x) + (size_t)i * 2;
        float4 v0 = src[0], v1 = src[1];
        float vf[8] = {v0.x, v0.y, v0.z, v0.w, v1.x, v1.y, v1.z, v1.w};
        union { ushort us[8]; uint4 u4; } o;
        #pragma unroll
        for (int j = 0; j < 8; ++j) o.us[j] = f32_to_bf16_rne(vf[j]);
        reinterpret_cast<uint4*>(xh)[i] = o.u4;
    } else {
        int i = (blockIdx.x - XB) * 256 + threadIdx.x;   // 0..4095
        if (i < 256) bucket_cur[i] = i * BCAP;
        if (i < NUM_GRAPHS * 64) { gsum[i] = 0.f; gsum2[i] = 0.f; }
        if (i < 64) gcnt[i] = 0.f;
    }
}

// ===========================================================================
// bin edges into fixed-capacity bucket regions.
// packed 8B: lo = src | (dst&511)<<17 ; hi = w f32 bits
// ===========================================================================
__global__ __launch_bounds__(A_THREADS) void binA_kernel(
    const int* __restrict__ src_idx, const int* __restrict__ dst_idx,
    const float* __restrict__ ea, int* __restrict__ bucket_cursor,
    unsigned long long* __restrict__ binned)
{
    __shared__ int hist[NBUCKETS];
    __shared__ int lbase[NBUCKETS];
    int tid = threadIdx.x;
    if (tid < NBUCKETS) hist[tid] = 0;
    __syncthreads();

    int base = blockIdx.x * A_CHUNK;
    int srcv[A_EPT], dstv[A_EPT];
    float wv[A_EPT];
    #pragma unroll
    for (int i = 0; i < A_EPT; ++i) {
        int e = base + i * A_THREADS + tid;
        if (e < N_EDGES) {
            srcv[i] = src_idx[e];
            dstv[i] = dst_idx[e];
            wv[i]   = ea[e];
            atomicAdd(&hist[dstv[i] >> BSHIFT], 1);
        } else {
            dstv[i] = -1; srcv[i] = 0; wv[i] = 0.f;
        }
    }
    __syncthreads();
    if (tid < NBUCKETS) lbase[tid] = atomicAdd(&bucket_cursor[tid], hist[tid]);
    __syncthreads();
    if (tid < NBUCKETS) hist[tid] = 0;
    __syncthreads();
    #pragma unroll
    for (int i = 0; i < A_EPT; ++i) {
        if (dstv[i] >= 0) {
            int b = dstv[i] >> BSHIFT;
            int r = atomicAdd(&hist[b], 1);
            unsigned int lo = (unsigned int)(srcv[i] | ((dstv[i] & (NPB - 1)) << 17));
            unsigned long long pv = (unsigned long long)lo |
                ((unsigned long long)__float_as_uint(wv[i]) << 32);
            binned[lbase[b] + r] = pv;
        }
    }
}

// ===========================================================================
// per-bucket counting sort -> offsets2[] (int2 beg,end) + packed 4B csr[]
// ===========================================================================
__global__ __launch_bounds__(256) void binB_kernel(
    const unsigned long long* __restrict__ binned,
    const int* __restrict__ bucket_cur,
    int2* __restrict__ offsets2, unsigned int* __restrict__ csr)
{
    __shared__ int dcnt[NPB];
    __shared__ int doff[NPB];
    __shared__ int psum[256];
    int tid = threadIdx.x;
    int b = blockIdx.x;
    int beg = b * BCAP;
    int n = bucket_cur[b] - beg;

    for (int i = tid; i < NPB; i += 256) dcnt[i] = 0;
    __syncthreads();
    for (int j = tid; j < n; j += 256) {
        unsigned long long pv = binned[beg + j];
        atomicAdd(&dcnt[((unsigned int)pv) >> 17], 1);
    }
    __syncthreads();
    int e0 = dcnt[2 * tid], e1 = dcnt[2 * tid + 1];
    psum[tid] = e0 + e1;
    __syncthreads();
    for (int off = 1; off < 256; off <<= 1) {
        int v = psum[tid];
        int a = (tid >= off) ? psum[tid - off] : 0;
        __syncthreads();
        psum[tid] = v + a;
        __syncthreads();
    }
    int ex = (tid == 0) ? 0 : psum[tid - 1];
    doff[2 * tid] = ex;
    doff[2 * tid + 1] = ex + e0;
    __syncthreads();
    for (int i = tid; i < NPB; i += 256) {
        int node = (b << BSHIFT) + i;
        if (node < N_NODES) {
            int s = beg + doff[i];
            int e = beg + ((i + 1 < NPB) ? doff[i + 1] : n);
            offsets2[node] = make_int2(s, e);
        }
        dcnt[i] = doff[i];
    }
    __syncthreads();
    for (int j = tid; j < n; j += 256) {
        unsigned long long pv = binned[beg + j];
        unsigned int lo = (unsigned int)pv;
        unsigned int wbits = (unsigned int)(pv >> 32);
        int dlo = lo >> 17;
        int r = atomicAdd(&dcnt[dlo], 1);
        unsigned int field = ((wbits + 0x7FFFu + ((wbits >> 16) & 1u)) >> 16) & 0x7FFFu;
        csr[beg + r] = (lo & 0x1FFFFu) | (field << 17);
    }
}

// ===========================================================================
// Gather-aggregate (bf16 x table, 4B csr, int2 offsets): wave per node.
// ===========================================================================
__global__ __launch_bounds__(256) void gatherh_kernel(
    const ushort* __restrict__ xh, const int2* __restrict__ offsets2,
    const unsigned int* __restrict__ csr, ushort* __restrict__ agg)
{
    int wid = (int)((blockIdx.x * blockDim.x + threadIdx.x) >> 6);
    if (wid >= N_NODES) return;
    int lane = threadIdx.x & 63;
    int2 o2 = offsets2[wid];
    int beg = __builtin_amdgcn_readfirstlane(o2.x);
    int end = __builtin_amdgcn_readfirstlane(o2.y);
    float acc[8];
    #pragma unroll
    for (int u = 0; u < 8; ++u) acc[u] = 0.f;
    int j = beg;
    for (; j + 7 < end; j += 8) {
        unsigned int e[8];
        #pragma unroll
        for (int u = 0; u < 8; ++u) e[u] = csr[j + u];
        float xv[8];
        #pragma unroll
        for (int u = 0; u < 8; ++u)
            xv[u] = __uint_as_float((unsigned int)xh[(size_t)(e[u] & 0x1FFFFu) * 64 + lane] << 16);
        #pragma unroll
        for (int u = 0; u < 8; ++u)
            acc[u] = fmaf(__uint_as_float((e[u] >> 17) << 16), xv[u], acc[u]);
    }
    for (; j < end; ++j) {
        unsigned int e0 = csr[j];
        float xv = __uint_as_float((unsigned int)xh[(size_t)(e0 & 0x1FFFFu) * 64 + lane] << 16);
        acc[0] = fmaf(__uint_as_float((e0 >> 17) << 16), xv, acc[0]);
    }
    float a = ((acc[0] + acc[1]) + (acc[2] + acc[3])) +
              ((acc[4] + acc[5]) + (acc[6] + acc[7]));
    agg[(size_t)wid * 64 + lane] = f32_to_bf16_rne(a);
}

// ===========================================================================
// Dense (MFMA, plain bf16) + FUSED per-graph stats.
// h = relu([agg|x] @ [W^T] + b) -> bf16; accumulate sum/sum^2/count per
// (graph,dim) via block-LDS (gspan<=8; sorted batch) with global fallback.
// ===========================================================================
#define DB 128
__global__ __launch_bounds__(256) void dense_mfma16_stats_kernel(
    const ushort* __restrict__ agg, const ushort* __restrict__ xh,
    ushort* __restrict__ hout,
    const float* __restrict__ W_rel, const float* __restrict__ b_rel,
    const float* __restrict__ W_root,
    const int* __restrict__ batch,
    float* __restrict__ gsum, float* __restrict__ gsum2,
    float* __restrict__ gcnt)
{
    __shared__ unsigned int Bf[4][4][64][4];   // 16 KB
    __shared__ float ls[8][64];                // 2 KB
    __shared__ float ls2[8][64];               // 2 KB
    __shared__ int lcnt[8];
    __shared__ int ginfo[2];
    int tid = threadIdx.x;
    int nbase = blockIdx.x * DB;

    #pragma unroll
    for (int g = 0; g < 8; ++g) {
        int q = tid * 8 + g;
        int i4   = (q & 1) * 4;
        int lane = (q >> 1) & 63;
        int dt   = (q >> 7) & 3;
        int kt   = (q >> 9) & 3;
        int d = dt * 16 + (lane & 15);
        int k = kt * 32 + (lane >> 4) * 8 + i4;
        const float* Wsrc = (k < 64) ? (W_rel + d * 64 + k)
                                     : (W_root + d * 64 + (k - 64));
        float4 w = *reinterpret_cast<const float4*>(Wsrc);
        unsigned int b0 = f32_to_bf16_rne(w.x);
        unsigned int b1 = f32_to_bf16_rne(w.y);
        unsigned int b2 = f32_to_bf16_rne(w.z);
        unsigned int b3 = f32_to_bf16_rne(w.w);
        int u = i4 >> 1;
        Bf[kt][dt][lane][u]     = b0 | (b1 << 16);
        Bf[kt][dt][lane][u + 1] = b2 | (b3 << 16);
    }
    for (int i = tid; i < 8 * 64; i += 256) { ls[i >> 6][i & 63] = 0.f; ls2[i >> 6][i & 63] = 0.f; }
    if (tid < 8) lcnt[tid] = 0;
    if (tid == 0) {
        int gb = batch[nbase];
        int last = min(nbase + DB - 1, N_NODES - 1);
        ginfo[0] = gb;
        ginfo[1] = batch[last] - gb + 1;
    }
    __syncthreads();

    int wid = tid >> 6, lane = tid & 63;
    int wbase = nbase + wid * 32;
    int r = lane & 15;
    int k0 = (lane >> 4) * 8;

    f32x4 acc[2][4];
    #pragma unroll
    for (int nt = 0; nt < 2; ++nt)
        #pragma unroll
        for (int dt = 0; dt < 4; ++dt)
            acc[nt][dt] = (f32x4){0.f, 0.f, 0.f, 0.f};

    bf16x8 zf;
    #pragma unroll
    for (int i = 0; i < 8; ++i) zf[i] = 0;

    #pragma unroll 1
    for (int kt = 0; kt < 4; ++kt) {
        bf16x8 bh[4];
        #pragma unroll
        for (int dt = 0; dt < 4; ++dt)
            bh[dt] = *reinterpret_cast<const bf16x8*>(&Bf[kt][dt][lane][0]);
        int kk = kt * 32 + k0;
        #pragma unroll
        for (int nt = 0; nt < 2; ++nt) {
            int node = wbase + nt * 16 + r;
            bool ok = (node < N_NODES);
            const ushort* srcrow = (kk < 64)
                ? (agg + (size_t)node * 64 + kk)
                : (xh + (size_t)node * 64 + (kk - 64));
            bf16x8 a = ok ? *reinterpret_cast<const bf16x8*>(srcrow) : zf;
            #pragma unroll
            for (int dt = 0; dt < 4; ++dt)
                acc[nt][dt] = __builtin_amdgcn_mfma_f32_16x16x32_bf16(a, bh[dt], acc[nt][dt], 0, 0, 0);
        }
    }

    int gbase = ginfo[0];
    bool fits = (ginfo[1] <= 8);
    float bias[4];
    #pragma unroll
    for (int dt = 0; dt < 4; ++dt) bias[dt] = b_rel[dt * 16 + r];

    int rowg = (lane >> 4) * 4;
    #pragma unroll
    for (int nt = 0; nt < 2; ++nt) {
        #pragma unroll
        for (int reg = 0; reg < 4; ++reg) {
            int node = wbase + nt * 16 + rowg + reg;
            if (node < N_NODES) {
                int g = batch[node];
                int gs = g - gbase;
                #pragma unroll
                for (int dt = 0; dt < 4; ++dt) {
                    int d = dt * 16 + r;
                    float v = fmaxf(acc[nt][dt][reg] + bias[dt], 0.f);
                    ushort hb = f32_to_bf16_rne(v);
                    hout[(size_t)node * 64 + d] = hb;
                    float vr = __uint_as_float((unsigned int)hb << 16);
                    if (fits) {
                        atomicAdd(&ls[gs][d], vr);
                        atomicAdd(&ls2[gs][d], vr * vr);
                    } else {
                        atomicAdd(&gsum[g * 64 + d], vr);
                        atomicAdd(&gsum2[g * 64 + d], vr * vr);
                    }
                }
            }
        }
    }
    // node counts (each node once per block)
    if (tid < DB) {
        int node = nbase + tid;
        if (node < N_NODES) {
            int g = batch[node];
            if (fits) atomicAdd(&lcnt[g - gbase], 1);
            else atomicAdd(&gcnt[g], 1.f);
        }
    }
    __syncthreads();
    if (fits) {
        int gspan = ginfo[1];
        for (int i = tid; i < gspan * 64; i += 256) {
            int gs = i >> 6, d = i & 63;
            float s = ls[gs][d];
            float s2 = ls2[gs][d];
            if (s != 0.f || s2 != 0.f) {
                atomicAdd(&gsum[(gbase + gs) * 64 + d], s);
                atomicAdd(&gsum2[(gbase + gs) * 64 + d], s2);
            }
        }
        if (tid < gspan && lcnt[tid] > 0)
            atomicAdd(&gcnt[gbase + tid], (float)lcnt[tid]);
    }
}

// ===========================================================================
// finalize: fold stats into per-(g,d) affine A,B
// ===========================================================================
__global__ __launch_bounds__(256) void finalize_kernel(
    const float* __restrict__ gsum,
    const float* __restrict__ gsum2,
    const float* __restrict__ gcnt,
    const float* __restrict__ gn_w,
    const float* __restrict__ gn_b,
    const float* __restrict__ gn_ms,
    float* __restrict__ Ag,
    float* __restrict__ Bg)
{
    int i = blockIdx.x * blockDim.x + threadIdx.x;
    if (i >= NUM_GRAPHS * 64) return;
    int g = i >> 6, d = i & 63;
    float c = fmaxf(gcnt[g], 1.f);
    float m = gsum[i] / c;
    float q = gsum2[i] / c;
    float s = gn_ms[d];
    float var = q - (2.f * s - s * s) * m * m;
    float inv = rsqrtf(fmaxf(var, 0.f) + EPS);
    float A = gn_w[d] * inv;
    Ag[i] = A;
    Bg[i] = gn_b[d] - A * s * m;
}

// ===========================================================================
// apply (bf16 h): out[n][d] = A[g][d]*h[n][d] + B[g][d]; 8 dims/thread
// ===========================================================================
__global__ __launch_bounds__(256) void apply16_kernel(
    const ushort* __restrict__ h,
    const int* __restrict__ batch,
    const float* __restrict__ Ag,
    const float* __restrict__ Bg,
    float* __restrict__ out)
{
    int i = blockIdx.x * blockDim.x + threadIdx.x;
    if (i >= N_NODES * 8) return;
    int n = i >> 3;
    int q = i & 7;
    int g = batch[n];
    union { uint4 u4; ushort us[8]; } hv;
    hv.u4 = *reinterpret_cast<const uint4*>(h + (size_t)n * 64 + q * 8);
    const float4* Av = reinterpret_cast<const float4*>(Ag + g * 64 + q * 8);
    const float4* Bv = reinterpret_cast<const float4*>(Bg + g * 64 + q * 8);
    float4 A0 = Av[0], A1 = Av[1];
    float4 B0 = Bv[0], B1 = Bv[1];
    float Af[8] = {A0.x, A0.y, A0.z, A0.w, A1.x, A1.y, A1.z, A1.w};
    float Bf_[8] = {B0.x, B0.y, B0.z, B0.w, B1.x, B1.y, B1.z, B1.w};
    float4 o0, o1;
    float of[8];
    #pragma unroll
    for (int j = 0; j < 8; ++j) {
        float v = __uint_as_float((unsigned int)hv.us[j] << 16);
        of[j] = fmaf(Af[j], v, Bf_[j]);
    }
    o0.x = of[0]; o0.y = of[1]; o0.z = of[2]; o0.w = of[3];
    o1.x = of[4]; o1.y = of[5]; o1.z = of[6]; o1.w = of[7];
    float4* op = reinterpret_cast<float4*>(out + (size_t)n * 64 + q * 8);
    op[0] = o0;
    op[1] = o1;
}

// ===========================================================================
// LEGACY PATH (fallback tiers, f32 h)
// ===========================================================================
__global__ __launch_bounds__(256) void hist_kernel(
    const int* __restrict__ dst_idx, int* __restrict__ deg)
{
    int e = blockIdx.x * blockDim.x + threadIdx.x;
    if (e >= N_EDGES) return;
    atomicAdd(&deg[dst_idx[e]], 1);
}

__global__ __launch_bounds__(SCAN_T) void scan1_kernel(
    const int* __restrict__ deg, int* __restrict__ offsets,
    int* __restrict__ blocksum)
{
    __shared__ int lds[SCAN_T];
    int b = blockIdx.x, t = threadIdx.x;
    int base = b * SCAN_CHUNK + t * SCAN_E;
    int v[SCAN_E];
    int s = 0;
    #pragma unroll
    for (int i = 0; i < SCAN_E; ++i) {
        v[i] = (base + i < N_NODES) ? deg[base + i] : 0;
        s += v[i];
    }
    lds[t] = s;
    __syncthreads();
    for (int off = 1; off < SCAN_T; off <<= 1) {
        int val = lds[t];
        int add = (t >= off) ? lds[t - off] : 0;
        __syncthreads();
        lds[t] = val + add;
        __syncthreads();
    }
    if (t == SCAN_T - 1) blocksum[b] = lds[SCAN_T - 1];
    int run = (t == 0) ? 0 : lds[t - 1];
    #pragma unroll
    for (int i = 0; i < SCAN_E; ++i) {
        if (base + i < N_NODES) offsets[base + i] = run;
        run += v[i];
    }
}

__global__ __launch_bounds__(64) void scan2_kernel(
    const int* __restrict__ blocksum, int* __restrict__ blockoff)
{
    __shared__ int lds[64];
    int t = threadIdx.x;
    lds[t] = (t < NSCAN) ? blocksum[t] : 0;
    __syncthreads();
    for (int off = 1; off < 64; off <<= 1) {
        int val = lds[t];
        int add = (t >= off) ? lds[t - off] : 0;
        __syncthreads();
        lds[t] = val + add;
        __syncthreads();
    }
    if (t < NSCAN) blockoff[t] = (t == 0) ? 0 : lds[t - 1];
}

__global__ __launch_bounds__(256) void scan3_kernel(
    int* __restrict__ offsets, const int* __restrict__ blockoff,
    int* __restrict__ cursor)
{
    int i = blockIdx.x * blockDim.x + threadIdx.x;
    if (i < N_NODES) {
        int v = offsets[i] + blockoff[i / SCAN_CHUNK];
        offsets[i] = v;
        cursor[i] = v;
    }
    if (i == 0) offsets[N_NODES] = N_EDGES;
}

__global__ __launch_bounds__(256) void fill_kernel(
    const int* __restrict__ src_idx, const int* __restrict__ dst_idx,
    const float* __restrict__ ea, int* __restrict__ cursor,
    int2* __restrict__ csr)
{
    int e = blockIdx.x * blockDim.x + threadIdx.x;
    if (e >= N_EDGES) return;
    int s = src_idx[e];
    int d = dst_idx[e];
    float w = ea[e];
    int pos = atomicAdd(&cursor[d], 1);
    csr[pos] = make_int2(s, __float_as_int(w));
}

__global__ __launch_bounds__(256) void gather_kernel(
    const float* __restrict__ x, const int* __restrict__ offsets,
    const int2* __restrict__ csr, float* __restrict__ agg)
{
    int wid = (int)((blockIdx.x * blockDim.x + threadIdx.x) >> 6);
    if (wid >= N_NODES) return;
    int lane = threadIdx.x & 63;
    int beg = __builtin_amdgcn_readfirstlane(offsets[wid]);
    int end = __builtin_amdgcn_readfirstlane(offsets[wid + 1]);
    float acc0 = 0.f, acc1 = 0.f;
    int j = beg;
    for (; j + 1 < end; j += 2) {
        int2 a = csr[j];
        int2 b = csr[j + 1];
        acc0 = fmaf(__int_as_float(a.y), x[(size_t)a.x * 64 + lane], acc0);
        acc1 = fmaf(__int_as_float(b.y), x[(size_t)b.x * 64 + lane], acc1);
    }
    if (j < end) {
        int2 a = csr[j];
        acc0 = fmaf(__int_as_float(a.y), x[(size_t)a.x * 64 + lane], acc0);
    }
    agg[(size_t)wid * 64 + lane] = acc0 + acc1;
}

__global__ __launch_bounds__(256) void scatter_kernel(
    const float* __restrict__ x,
    const int* __restrict__ src_idx,
    const int* __restrict__ dst_idx,
    const float* __restrict__ ea,
    float* __restrict__ agg)
{
    long long gid = (long long)blockIdx.x * blockDim.x + threadIdx.x;
    if (gid >= (long long)N_EDGES * 16) return;
    int e = (int)(gid >> 4);
    int q = (int)(gid & 15);
    int s = src_idx[e];
    int d = dst_idx[e];
    float w = ea[e];
    float4 v = reinterpret_cast<const float4*>(x)[(size_t)s * 16 + q];
    float* out = agg + (size_t)d * 64 + q * 4;
    atomicAdd(out + 0, w * v.x);
    atomicAdd(out + 1, w * v.y);
    atomicAdd(out + 2, w * v.z);
    atomicAdd(out + 3, w * v.w);
}

// fallback dense (f32 agg/x inputs, in-place, split-precision) — tiers 2/3
__global__ __launch_bounds__(256) void dense_mfma_kernel(
    float* __restrict__ aggh,
    const float* __restrict__ x,
    const float* __restrict__ W_rel,
    const float* __restrict__ b_rel,
    const float* __restrict__ W_root)
{
    __shared__ unsigned int Bf[2][4][4][64][4];
    int tid = threadIdx.x;
    #pragma unroll
    for (int g = 0; g < 8; ++g) {
        int q = tid * 8 + g;
        int i4   = (q & 1) * 4;
        int lane = (q >> 1) & 63;
        int dt   = (q >> 7) & 3;
        int kt   = (q >> 9) & 3;
        int d = dt * 16 + (lane & 15);
        int k = kt * 32 + (lane >> 4) * 8 + i4;
        const float* Wsrc = (k < 64) ? (W_rel + d * 64 + k)
                                     : (W_root + d * 64 + (k - 64));
        float4 w = *reinterpret_cast<const float4*>(Wsrc);
        float wf[4] = {w.x, w.y, w.z, w.w};
        unsigned int hi[4], lo[4];
        #pragma unroll
        for (int j = 0; j < 4; ++j) {
            unsigned int bits = __float_as_uint(wf[j]);
            hi[j] = bits >> 16;
            float resid = wf[j] - __uint_as_float(bits & 0xFFFF0000u);
            lo[j] = __float_as_uint(resid) >> 16;
        }
        int u = i4 >> 1;
        Bf[0][kt][dt][lane][u]     = hi[0] | (hi[1] << 16);
        Bf[0][kt][dt][lane][u + 1] = hi[2] | (hi[3] << 16);
        Bf[1][kt][dt][lane][u]     = lo[0] | (lo[1] << 16);
        Bf[1][kt][dt][lane][u + 1] = lo[2] | (lo[3] << 16);
    }
    __syncthreads();

    int wid = tid >> 6, lane = tid & 63;
    int nbase = blockIdx.x * DB + wid * 32;
    int r = lane & 15;
    int k0 = (lane >> 4) * 8;

    f32x4 acc[2][4];
    #pragma unroll
    for (int nt = 0; nt < 2; ++nt)
        #pragma unroll
        for (int dt = 0; dt < 4; ++dt)
            acc[nt][dt] = (f32x4){0.f, 0.f, 0.f, 0.f};

    #pragma unroll 1
    for (int kt = 0; kt < 4; ++kt) {
        bf16x8 bh[4], bl[4];
        #pragma unroll
        for (int dt = 0; dt < 4; ++dt) {
            bh[dt] = *reinterpret_cast<const bf16x8*>(&Bf[0][kt][dt][lane][0]);
            bl[dt] = *reinterpret_cast<const bf16x8*>(&Bf[1][kt][dt][lane][0]);
        }
        int kk = kt * 32 + k0;
        #pragma unroll
        for (int nt = 0; nt < 2; ++nt) {
            int node = nbase + nt * 16 + r;
            float av[8];
            if (node < N_NODES) {
                const float* srcrow = (kk < 64)
                    ? (aggh + (size_t)node * 64 + kk)
                    : (x + (size_t)node * 64 + (kk - 64));
                float4 v0 = reinterpret_cast<const float4*>(srcrow)[0];
                float4 v1 = reinterpret_cast<const float4*>(srcrow)[1];
                av[0] = v0.x; av[1] = v0.y; av[2] = v0.z; av[3] = v0.w;
                av[4] = v1.x; av[5] = v1.y; av[6] = v1.z; av[7] = v1.w;
            } else {
                #pragma unroll
                for (int i = 0; i < 8; ++i) av[i] = 0.f;
            }
            bf16x8 ah, al;
            #pragma unroll
            for (int i = 0; i < 8; ++i) {
                unsigned int bits = __float_as_uint(av[i]);
                ah[i] = (short)(bits >> 16);
                float resid = av[i] - __uint_as_float(bits & 0xFFFF0000u);
                al[i] = (short)(__float_as_uint(resid) >> 16);
            }
            #pragma unroll
            for (int dt = 0; dt < 4; ++dt) {
                acc[nt][dt] = __builtin_amdgcn_mfma_f32_16x16x32_bf16(ah, bh[dt], acc[nt][dt], 0, 0, 0);
                acc[nt][dt] = __builtin_amdgcn_mfma_f32_16x16x32_bf16(al, bh[dt], acc[nt][dt], 0, 0, 0);
                acc[nt][dt] = __builtin_amdgcn_mfma_f32_16x16x32_bf16(ah, bl[dt], acc[nt][dt], 0, 0, 0);
            }
        }
    }

    int rowg = (lane >> 4) * 4;
    #pragma unroll
    for (int dt = 0; dt < 4; ++dt) {
        int d = dt * 16 + r;
        float bias = b_rel[d];
        #pragma unroll
        for (int nt = 0; nt < 2; ++nt) {
            #pragma unroll
            for (int reg = 0; reg < 4; ++reg) {
                int node = nbase + nt * 16 + rowg + reg;
                if (node < N_NODES) {
                    float v = fmaxf(acc[nt][dt][reg] + bias, 0.f);
                    aggh[(size_t)node * 64 + d] = v;
                }
            }
        }
    }
}

#define NPW 32
__global__ __launch_bounds__(256) void stats_kernel(
    const float* __restrict__ h,
    const int* __restrict__ batch,
    float* __restrict__ gsum,
    float* __restrict__ gsum2,
    float* __restrict__ gcnt)
{
    int wave = (int)((blockIdx.x * blockDim.x + threadIdx.x) >> 6);
    int lane = threadIdx.x & 63;
    int base = wave * NPW;
    if (base >= N_NODES) return;
    int end = min(base + NPW, N_NODES);

    int gcur = batch[base];
    float s = 0.f, s2 = 0.f, cnt = 0.f;
    for (int n = base; n < end; ++n) {
        int g = batch[n];
        if (g != gcur) {
            atomicAdd(&gsum[gcur * 64 + lane], s);
            atomicAdd(&gsum2[gcur * 64 + lane], s2);
            if (lane == 0) atomicAdd(&gcnt[gcur], cnt);
            s = 0.f; s2 = 0.f; cnt = 0.f;
            gcur = g;
        }
        float v = h[(size_t)n * 64 + lane];
        s += v;
        s2 = fmaf(v, v, s2);
        cnt += 1.f;
    }
    atomicAdd(&gsum[gcur * 64 + lane], s);
    atomicAdd(&gsum2[gcur * 64 + lane], s2);
    if (lane == 0) atomicAdd(&gcnt[gcur], cnt);
}

__global__ __launch_bounds__(256) void apply_kernel(
    const float* __restrict__ h,
    const int* __restrict__ batch,
    const float* __restrict__ Ag,
    const float* __restrict__ Bg,
    float* __restrict__ out)
{
    long long gid = (long long)blockIdx.x * blockDim.x + threadIdx.x;
    if (gid >= (long long)N_NODES * 16) return;
    int n = (int)(gid >> 4);
    int q = (int)(gid & 15);
    int g = batch[n];
    float4 hv = reinterpret_cast<const float4*>(h)[gid];
    float4 A = reinterpret_cast<const float4*>(Ag)[g * 16 + q];
    float4 B = reinterpret_cast<const float4*>(Bg)[g * 16 + q];
    float4 o;
    o.x = fmaf(A.x, hv.x, B.x);
    o.y = fmaf(A.y, hv.y, B.y);
    o.z = fmaf(A.z, hv.z, B.z);
    o.w = fmaf(A.w, hv.w, B.w);
    reinterpret_cast<float4*>(out)[gid] = o;
}

// ===========================================================================
extern "C" void kernel_launch(void* const* d_in, const int* in_sizes, int n_in,
                              void* d_out, int out_size, void* d_ws, size_t ws_size,
                              hipStream_t stream)
{
    const float* x      = (const float*)d_in[0];
    const int*   ei     = (const int*)d_in[1];
    const float* ea     = (const float*)d_in[2];
    const int*   batch  = (const int*)d_in[3];
    const float* W_rel  = (const float*)d_in[4];
    const float* b_rel  = (const float*)d_in[5];
    const float* W_root = (const float*)d_in[6];
    const float* gn_w   = (const float*)d_in[7];
    const float* gn_b   = (const float*)d_in[8];
    const float* gn_ms  = (const float*)d_in[9];
    const int* src_idx = ei;
    const int* dst_idx = ei + N_EDGES;

    char* wsp = (char*)d_ws;

    // ---------------- tier-1 layout (fixed-capacity buckets) ----------------
    int*   bucket_cur  = (int*)wsp;                                   // 256
    float* gsumN       = (float*)(bucket_cur + 256);                  // G*64
    float* gsum2N      = gsumN + NUM_GRAPHS * 64;                     // G*64
    float* gcntN       = gsum2N + NUM_GRAPHS * 64;                    // 64
    int2*  offsets2    = (int2*)(gcntN + 64);                         // N int2
    size_t regA_off    = (((size_t)((char*)(offsets2 + N_NODES) - wsp)) + 15) & ~(size_t)15;
    size_t binned_sz   = (size_t)NBUCKETS * BCAP * 8;
    size_t hbuf_sz     = (size_t)N_NODES * 64 * 2;
    size_t regA_sz     = (binned_sz > hbuf_sz ? binned_sz : hbuf_sz);
    unsigned long long* binned = (unsigned long long*)(wsp + regA_off);
    ushort* hbuf16     = (ushort*)(wsp + regA_off);
    unsigned int* csrN = (unsigned int*)(wsp + regA_off + regA_sz);   // NBUCKETS*BCAP*4B
    ushort* aggN       = (ushort*)((char*)csrN + (size_t)NBUCKETS * BCAP * 4);
    float*  AgN        = (float*)(aggN + (size_t)N_NODES * 64);
    float*  BgN        = AgN + NUM_GRAPHS * 64;
    ushort* xh         = (ushort*)(BgN + NUM_GRAPHS * 64);
    size_t reqN        = (size_t)((char*)(xh + (size_t)N_NODES * 64) - wsp);

    // ---------------- legacy layouts (tiers 2/3) ----------------
    int*   degL     = (int*)wsp;
    float* gsumL    = (float*)(degL + N_NODES);
    float* gsum2L   = gsumL + NUM_GRAPHS * 64;
    float* gcntL    = gsum2L + NUM_GRAPHS * 64;
    size_t zeroL    = ((size_t)N_NODES + 2 * NUM_GRAPHS * 64 + 64) * 4;
    int*   offsetsL = (int*)(gcntL + 64);
    int*   blocksum = offsetsL + N_NODES + 1;
    int*   blockoff = blocksum + 64;
    int*   cursorL  = blockoff + 64;
    size_t csrL_off = (((size_t)((char*)(cursorL + N_NODES) - wsp)) + 15) & ~(size_t)15;
    int2*  csrL     = (int2*)(wsp + csrL_off);
    float* aggL     = (float*)(csrL + N_EDGES);
    float* AgL      = aggL + (size_t)N_NODES * 64;
    float* BgL      = AgL + NUM_GRAPHS * 64;
    size_t reqL     = (size_t)((char*)(BgL + NUM_GRAPHS * 64) - wsp);

    if (ws_size >= reqN) {
        // ---------- tier 1 (7 launches) ----------
        xcast_init_kernel<<<XB + 16, 256, 0, stream>>>(
            x, xh, bucket_cur, gsumN, gsum2N, gcntN);
        binA_kernel<<<NBLK_A, A_THREADS, 0, stream>>>(src_idx, dst_idx, ea, bucket_cur, binned);
        binB_kernel<<<NBUCKETS, 256, 0, stream>>>(binned, bucket_cur, offsets2, csrN);
        gatherh_kernel<<<(N_NODES + 3) / 4, 256, 0, stream>>>(xh, offsets2, csrN, aggN);
        dense_mfma16_stats_kernel<<<(N_NODES + DB - 1) / DB, 256, 0, stream>>>(
            aggN, xh, hbuf16, W_rel, b_rel, W_root, batch, gsumN, gsum2N, gcntN);
        finalize_kernel<<<(NUM_GRAPHS * 64 + 255) / 256, 256, 0, stream>>>(
            gsumN, gsum2N, gcntN, gn_w, gn_b, gn_ms, AgN, BgN);
        apply16_kernel<<<(N_NODES * 8 + 255) / 256, 256, 0, stream>>>(
            hbuf16, batch, AgN, BgN, (float*)d_out);
    } else if (ws_size >= reqL) {
        // ---------- tier 2: legacy CSR (f32) ----------
        hipMemsetAsync(d_ws, 0, zeroL, stream);
        hist_kernel<<<(N_EDGES + 255) / 256, 256, 0, stream>>>(dst_idx, degL);
        scan1_kernel<<<NSCAN, SCAN_T, 0, stream>>>(degL, offsetsL, blocksum);
        scan2_kernel<<<1, 64, 0, stream>>>(blocksum, blockoff);
        scan3_kernel<<<(N_NODES + 255) / 256, 256, 0, stream>>>(offsetsL, blockoff, cursorL);
        fill_kernel<<<(N_EDGES + 255) / 256, 256, 0, stream>>>(src_idx, dst_idx, ea, cursorL, csrL);
        gather_kernel<<<(N_NODES + 3) / 4, 256, 0, stream>>>(x, offsetsL, csrL, aggL);
        dense_mfma_kernel<<<(N_NODES + DB - 1) / DB, 256, 0, stream>>>(
            aggL, x, W_rel, b_rel, W_root);
        {
            int waves = (N_NODES + NPW - 1) / NPW;
            stats_kernel<<<(waves + 3) / 4, 256, 0, stream>>>(aggL, batch, gsumL, gsum2L, gcntL);
        }
        finalize_kernel<<<(NUM_GRAPHS * 64 + 255) / 256, 256, 0, stream>>>(
            gsumL, gsum2L, gcntL, gn_w, gn_b, gn_ms, AgL, BgL);
        {
            long long total = (long long)N_NODES * 16;
            apply_kernel<<<(int)((total + 255) / 256), 256, 0, stream>>>(
                aggL, batch, AgL, BgL, (float*)d_out);
        }
    } else {
        // ---------- tier 3: atomic scatter ----------
        float* agg = (float*)(gcntL + 64);
        float* Ag  = agg + (size_t)N_NODES * 64;
        float* Bg  = Ag + NUM_GRAPHS * 64;
        size_t zb = zeroL + (size_t)N_NODES * 64 * 4;
        hipMemsetAsync(d_ws, 0, zb, stream);
        long long total = (long long)N_EDGES * 16;
        scatter_kernel<<<(int)((total + 255) / 256), 256, 0, stream>>>(
            x, src_idx, dst_idx, ea, agg);
        dense_mfma_kernel<<<(N_NODES + DB - 1) / DB, 256, 0, stream>>>(
            agg, x, W_rel, b_rel, W_root);
        {
            int waves = (N_NODES + NPW - 1) / NPW;
            stats_kernel<<<(waves + 3) / 4, 256, 0, stream>>>(agg, batch, gsumL, gsum2L, gcntL);
        }
        finalize_kernel<<<(NUM_GRAPHS * 64 + 255) / 256, 256, 0, stream>>>(
            gsumL, gsum2L, gcntL, gn_w, gn_b, gn_ms, Ag, Bg);
        {
            long long t2 = (long long)N_NODES * 16;
            apply_kernel<<<(int)((t2 + 255) / 256), 256, 0, stream>>>(
                agg, batch, Ag, Bg, (float*)d_out);
        }
    }
}

// Round 13
// 152.734 us; speedup vs baseline: 1.3034x; 1.3034x over previous
//
#include <hip/hip_runtime.h>

#define N_NODES 100000
#define N_EDGES 1600000
#define D 64
#define NUM_GRAPHS 64
#define EPS 1e-5f

// ---- bucketed CSR build params ----
#define BSHIFT 9
#define NPB 512
#define NBUCKETS ((N_NODES + NPB - 1) / NPB)      // 196
#define BCAP 12288                                 // fixed bucket capacity
#define A_THREADS 1024
#define A_EPT 8
#define A_CHUNK (A_THREADS * A_EPT)               // 8192
#define NBLK_A ((N_EDGES + A_CHUNK - 1) / A_CHUNK) // 196
#define XB ((N_NODES * 64 / 8 + 255) / 256)       // xcast blocks (3125)

// ---- legacy scan params (fallback path) ----
#define SCAN_T 256
#define SCAN_E 8
#define SCAN_CHUNK (SCAN_T * SCAN_E)
#define NSCAN ((N_NODES + SCAN_CHUNK - 1) / SCAN_CHUNK)

typedef float f32x4 __attribute__((ext_vector_type(4)));
typedef short bf16x8 __attribute__((ext_vector_type(8)));

__device__ __forceinline__ ushort f32_to_bf16_rne(float v) {
    unsigned int bits = __float_as_uint(v);
    return (ushort)((bits + 0x7FFFu + ((bits >> 16) & 1u)) >> 16);
}

// ===========================================================================
// fused: blocks [0,XB) cast x->bf16; blocks [XB,XB+16) init cursors + stats
// ===========================================================================
__global__ __launch_bounds__(256) void xcast_init_kernel(
    const float* __restrict__ x, ushort* __restrict__ xh,
    int* __restrict__ bucket_cur, float* __restrict__ gsum,
    float* __restrict__ gsum2, float* __restrict__ gcnt)
{
    if (blockIdx.x < XB) {
        int i = blockIdx.x * blockDim.x + threadIdx.x;
        if (i >= N_NODES * 64 / 8) return;
        const float4* src = reinterpret_cast<const float4*>(x) + (size_t)i * 2;
        float4 v0 = src[0], v1 = src[1];
        float vf[8] = {v0.x, v0.y, v0.z, v0.w, v1.x, v1.y, v1.z, v1.w};
        union { ushort us[8]; uint4 u4; } o;
        #pragma unroll
        for (int j = 0; j < 8; ++j) o.us[j] = f32_to_bf16_rne(vf[j]);
        reinterpret_cast<uint4*>(xh)[i] = o.u4;
    } else {
        int i = (blockIdx.x - XB) * 256 + threadIdx.x;
        if (i < 256) bucket_cur[i] = i * BCAP;
        if (i < NUM_GRAPHS * 64) { gsum[i] = 0.f; gsum2[i] = 0.f; }
        if (i < 64) gcnt[i] = 0.f;
    }
}

// ===========================================================================
// bin edges into fixed-capacity bucket regions.
// packed 8B: lo = src | (dst&511)<<17 ; hi = w f32 bits
// ===========================================================================
__global__ __launch_bounds__(A_THREADS) void binA_kernel(
    const int* __restrict__ src_idx, const int* __restrict__ dst_idx,
    const float* __restrict__ ea, int* __restrict__ bucket_cursor,
    unsigned long long* __restrict__ binned)
{
    __shared__ int hist[NBUCKETS];
    __shared__ int lbase[NBUCKETS];
    int tid = threadIdx.x;
    if (tid < NBUCKETS) hist[tid] = 0;
    __syncthreads();

    int base = blockIdx.x * A_CHUNK;
    int srcv[A_EPT], dstv[A_EPT];
    float wv[A_EPT];
    #pragma unroll
    for (int i = 0; i < A_EPT; ++i) {
        int e = base + i * A_THREADS + tid;
        if (e < N_EDGES) {
            srcv[i] = src_idx[e];
            dstv[i] = dst_idx[e];
            wv[i]   = ea[e];
            atomicAdd(&hist[dstv[i] >> BSHIFT], 1);
        } else {
            dstv[i] = -1; srcv[i] = 0; wv[i] = 0.f;
        }
    }
    __syncthreads();
    if (tid < NBUCKETS) lbase[tid] = atomicAdd(&bucket_cursor[tid], hist[tid]);
    __syncthreads();
    if (tid < NBUCKETS) hist[tid] = 0;
    __syncthreads();
    #pragma unroll
    for (int i = 0; i < A_EPT; ++i) {
        if (dstv[i] >= 0) {
            int b = dstv[i] >> BSHIFT;
            int r = atomicAdd(&hist[b], 1);
            unsigned int lo = (unsigned int)(srcv[i] | ((dstv[i] & (NPB - 1)) << 17));
            unsigned long long pv = (unsigned long long)lo |
                ((unsigned long long)__float_as_uint(wv[i]) << 32);
            binned[lbase[b] + r] = pv;
        }
    }
}

// ===========================================================================
// per-bucket counting sort -> offsets2[] (int2 beg,end) + packed 4B csr[]
// ===========================================================================
__global__ __launch_bounds__(256) void binB_kernel(
    const unsigned long long* __restrict__ binned,
    const int* __restrict__ bucket_cur,
    int2* __restrict__ offsets2, unsigned int* __restrict__ csr)
{
    __shared__ int dcnt[NPB];
    __shared__ int doff[NPB];
    __shared__ int psum[256];
    int tid = threadIdx.x;
    int b = blockIdx.x;
    int beg = b * BCAP;
    int n = bucket_cur[b] - beg;

    for (int i = tid; i < NPB; i += 256) dcnt[i] = 0;
    __syncthreads();
    for (int j = tid; j < n; j += 256) {
        unsigned long long pv = binned[beg + j];
        atomicAdd(&dcnt[((unsigned int)pv) >> 17], 1);
    }
    __syncthreads();
    int e0 = dcnt[2 * tid], e1 = dcnt[2 * tid + 1];
    psum[tid] = e0 + e1;
    __syncthreads();
    for (int off = 1; off < 256; off <<= 1) {
        int v = psum[tid];
        int a = (tid >= off) ? psum[tid - off] : 0;
        __syncthreads();
        psum[tid] = v + a;
        __syncthreads();
    }
    int ex = (tid == 0) ? 0 : psum[tid - 1];
    doff[2 * tid] = ex;
    doff[2 * tid + 1] = ex + e0;
    __syncthreads();
    for (int i = tid; i < NPB; i += 256) {
        int node = (b << BSHIFT) + i;
        if (node < N_NODES) {
            int s = beg + doff[i];
            int e = beg + ((i + 1 < NPB) ? doff[i + 1] : n);
            offsets2[node] = make_int2(s, e);
        }
        dcnt[i] = doff[i];
    }
    __syncthreads();
    for (int j = tid; j < n; j += 256) {
        unsigned long long pv = binned[beg + j];
        unsigned int lo = (unsigned int)pv;
        unsigned int wbits = (unsigned int)(pv >> 32);
        int dlo = lo >> 17;
        int r = atomicAdd(&dcnt[dlo], 1);
        unsigned int field = ((wbits + 0x7FFFu + ((wbits >> 16) & 1u)) >> 16) & 0x7FFFu;
        csr[beg + r] = (lo & 0x1FFFFu) | (field << 17);
    }
}

// ===========================================================================
// Gather-aggregate (bf16 x table, 4B csr, int2 offsets): wave per node.
// ===========================================================================
__global__ __launch_bounds__(256) void gatherh_kernel(
    const ushort* __restrict__ xh, const int2* __restrict__ offsets2,
    const unsigned int* __restrict__ csr, ushort* __restrict__ agg)
{
    int wid = (int)((blockIdx.x * blockDim.x + threadIdx.x) >> 6);
    if (wid >= N_NODES) return;
    int lane = threadIdx.x & 63;
    int2 o2 = offsets2[wid];
    int beg = __builtin_amdgcn_readfirstlane(o2.x);
    int end = __builtin_amdgcn_readfirstlane(o2.y);
    float acc[8];
    #pragma unroll
    for (int u = 0; u < 8; ++u) acc[u] = 0.f;
    int j = beg;
    for (; j + 7 < end; j += 8) {
        unsigned int e[8];
        #pragma unroll
        for (int u = 0; u < 8; ++u) e[u] = csr[j + u];
        float xv[8];
        #pragma unroll
        for (int u = 0; u < 8; ++u)
            xv[u] = __uint_as_float((unsigned int)xh[(size_t)(e[u] & 0x1FFFFu) * 64 + lane] << 16);
        #pragma unroll
        for (int u = 0; u < 8; ++u)
            acc[u] = fmaf(__uint_as_float((e[u] >> 17) << 16), xv[u], acc[u]);
    }
    for (; j < end; ++j) {
        unsigned int e0 = csr[j];
        float xv = __uint_as_float((unsigned int)xh[(size_t)(e0 & 0x1FFFFu) * 64 + lane] << 16);
        acc[0] = fmaf(__uint_as_float((e0 >> 17) << 16), xv, acc[0]);
    }
    float a = ((acc[0] + acc[1]) + (acc[2] + acc[3])) +
              ((acc[4] + acc[5]) + (acc[6] + acc[7]));
    agg[(size_t)wid * 64 + lane] = f32_to_bf16_rne(a);
}

// ===========================================================================
// Dense (MFMA, plain bf16 inputs): h = relu([agg|x] @ [W^T] + b) -> bf16
// (r11-proven version; no fused stats)
// ===========================================================================
#define DB 128
__global__ __launch_bounds__(256) void dense_mfma16_kernel(
    const ushort* __restrict__ agg, const ushort* __restrict__ xh,
    ushort* __restrict__ hout,
    const float* __restrict__ W_rel, const float* __restrict__ b_rel,
    const float* __restrict__ W_root)
{
    __shared__ unsigned int Bf[4][4][64][4];   // 16 KB
    int tid = threadIdx.x;

    #pragma unroll
    for (int g = 0; g < 8; ++g) {
        int q = tid * 8 + g;
        int i4   = (q & 1) * 4;
        int lane = (q >> 1) & 63;
        int dt   = (q >> 7) & 3;
        int kt   = (q >> 9) & 3;
        int d = dt * 16 + (lane & 15);
        int k = kt * 32 + (lane >> 4) * 8 + i4;
        const float* Wsrc = (k < 64) ? (W_rel + d * 64 + k)
                                     : (W_root + d * 64 + (k - 64));
        float4 w = *reinterpret_cast<const float4*>(Wsrc);
        unsigned int b0 = f32_to_bf16_rne(w.x);
        unsigned int b1 = f32_to_bf16_rne(w.y);
        unsigned int b2 = f32_to_bf16_rne(w.z);
        unsigned int b3 = f32_to_bf16_rne(w.w);
        int u = i4 >> 1;
        Bf[kt][dt][lane][u]     = b0 | (b1 << 16);
        Bf[kt][dt][lane][u + 1] = b2 | (b3 << 16);
    }
    __syncthreads();

    int wid = tid >> 6, lane = tid & 63;
    int nbase = blockIdx.x * DB + wid * 32;
    int r = lane & 15;
    int k0 = (lane >> 4) * 8;

    f32x4 acc[2][4];
    #pragma unroll
    for (int nt = 0; nt < 2; ++nt)
        #pragma unroll
        for (int dt = 0; dt < 4; ++dt)
            acc[nt][dt] = (f32x4){0.f, 0.f, 0.f, 0.f};

    bf16x8 zf;
    #pragma unroll
    for (int i = 0; i < 8; ++i) zf[i] = 0;

    #pragma unroll 1
    for (int kt = 0; kt < 4; ++kt) {
        bf16x8 bh[4];
        #pragma unroll
        for (int dt = 0; dt < 4; ++dt)
            bh[dt] = *reinterpret_cast<const bf16x8*>(&Bf[kt][dt][lane][0]);
        int kk = kt * 32 + k0;
        #pragma unroll
        for (int nt = 0; nt < 2; ++nt) {
            int node = nbase + nt * 16 + r;
            bool ok = (node < N_NODES);
            const ushort* srcrow = (kk < 64)
                ? (agg + (size_t)node * 64 + kk)
                : (xh + (size_t)node * 64 + (kk - 64));
            bf16x8 a = ok ? *reinterpret_cast<const bf16x8*>(srcrow) : zf;
            #pragma unroll
            for (int dt = 0; dt < 4; ++dt)
                acc[nt][dt] = __builtin_amdgcn_mfma_f32_16x16x32_bf16(a, bh[dt], acc[nt][dt], 0, 0, 0);
        }
    }

    int rowg = (lane >> 4) * 4;
    #pragma unroll
    for (int dt = 0; dt < 4; ++dt) {
        int d = dt * 16 + r;
        float bias = b_rel[d];
        #pragma unroll
        for (int nt = 0; nt < 2; ++nt) {
            #pragma unroll
            for (int reg = 0; reg < 4; ++reg) {
                int node = nbase + nt * 16 + rowg + reg;
                if (node < N_NODES) {
                    float v = fmaxf(acc[nt][dt][reg] + bias, 0.f);
                    hout[(size_t)node * 64 + d] = f32_to_bf16_rne(v);
                }
            }
        }
    }
}

// ===========================================================================
// stats (bf16 h): per-(graph, dim) sum, sum^2, count
// ===========================================================================
#define NPW 32
__global__ __launch_bounds__(256) void stats16_kernel(
    const ushort* __restrict__ h,
    const int* __restrict__ batch,
    float* __restrict__ gsum,
    float* __restrict__ gsum2,
    float* __restrict__ gcnt)
{
    int wave = (int)((blockIdx.x * blockDim.x + threadIdx.x) >> 6);
    int lane = threadIdx.x & 63;
    int base = wave * NPW;
    if (base >= N_NODES) return;
    int end = min(base + NPW, N_NODES);

    int gcur = batch[base];
    float s = 0.f, s2 = 0.f, cnt = 0.f;
    for (int n = base; n < end; ++n) {
        int g = batch[n];
        if (g != gcur) {
            atomicAdd(&gsum[gcur * 64 + lane], s);
            atomicAdd(&gsum2[gcur * 64 + lane], s2);
            if (lane == 0) atomicAdd(&gcnt[gcur], cnt);
            s = 0.f; s2 = 0.f; cnt = 0.f;
            gcur = g;
        }
        float v = __uint_as_float((unsigned int)h[(size_t)n * 64 + lane] << 16);
        s += v;
        s2 = fmaf(v, v, s2);
        cnt += 1.f;
    }
    atomicAdd(&gsum[gcur * 64 + lane], s);
    atomicAdd(&gsum2[gcur * 64 + lane], s2);
    if (lane == 0) atomicAdd(&gcnt[gcur], cnt);
}

// ===========================================================================
// finalize: fold stats into per-(g,d) affine A,B
// ===========================================================================
__global__ __launch_bounds__(256) void finalize_kernel(
    const float* __restrict__ gsum,
    const float* __restrict__ gsum2,
    const float* __restrict__ gcnt,
    const float* __restrict__ gn_w,
    const float* __restrict__ gn_b,
    const float* __restrict__ gn_ms,
    float* __restrict__ Ag,
    float* __restrict__ Bg)
{
    int i = blockIdx.x * blockDim.x + threadIdx.x;
    if (i >= NUM_GRAPHS * 64) return;
    int g = i >> 6, d = i & 63;
    float c = fmaxf(gcnt[g], 1.f);
    float m = gsum[i] / c;
    float q = gsum2[i] / c;
    float s = gn_ms[d];
    float var = q - (2.f * s - s * s) * m * m;
    float inv = rsqrtf(fmaxf(var, 0.f) + EPS);
    float A = gn_w[d] * inv;
    Ag[i] = A;
    Bg[i] = gn_b[d] - A * s * m;
}

// ===========================================================================
// apply (bf16 h): out[n][d] = A[g][d]*h[n][d] + B[g][d]; 8 dims/thread
// ===========================================================================
__global__ __launch_bounds__(256) void apply16_kernel(
    const ushort* __restrict__ h,
    const int* __restrict__ batch,
    const float* __restrict__ Ag,
    const float* __restrict__ Bg,
    float* __restrict__ out)
{
    int i = blockIdx.x * blockDim.x + threadIdx.x;
    if (i >= N_NODES * 8) return;
    int n = i >> 3;
    int q = i & 7;
    int g = batch[n];
    union { uint4 u4; ushort us[8]; } hv;
    hv.u4 = *reinterpret_cast<const uint4*>(h + (size_t)n * 64 + q * 8);
    const float4* Av = reinterpret_cast<const float4*>(Ag + g * 64 + q * 8);
    const float4* Bv = reinterpret_cast<const float4*>(Bg + g * 64 + q * 8);
    float4 A0 = Av[0], A1 = Av[1];
    float4 B0 = Bv[0], B1 = Bv[1];
    float Af[8] = {A0.x, A0.y, A0.z, A0.w, A1.x, A1.y, A1.z, A1.w};
    float Bf_[8] = {B0.x, B0.y, B0.z, B0.w, B1.x, B1.y, B1.z, B1.w};
    float4 o0, o1;
    float of[8];
    #pragma unroll
    for (int j = 0; j < 8; ++j) {
        float v = __uint_as_float((unsigned int)hv.us[j] << 16);
        of[j] = fmaf(Af[j], v, Bf_[j]);
    }
    o0.x = of[0]; o0.y = of[1]; o0.z = of[2]; o0.w = of[3];
    o1.x = of[4]; o1.y = of[5]; o1.z = of[6]; o1.w = of[7];
    float4* op = reinterpret_cast<float4*>(out + (size_t)n * 64 + q * 8);
    op[0] = o0;
    op[1] = o1;
}

// ===========================================================================
// LEGACY PATH (fallback tiers, f32 h)
// ===========================================================================
__global__ __launch_bounds__(256) void hist_kernel(
    const int* __restrict__ dst_idx, int* __restrict__ deg)
{
    int e = blockIdx.x * blockDim.x + threadIdx.x;
    if (e >= N_EDGES) return;
    atomicAdd(&deg[dst_idx[e]], 1);
}

__global__ __launch_bounds__(SCAN_T) void scan1_kernel(
    const int* __restrict__ deg, int* __restrict__ offsets,
    int* __restrict__ blocksum)
{
    __shared__ int lds[SCAN_T];
    int b = blockIdx.x, t = threadIdx.x;
    int base = b * SCAN_CHUNK + t * SCAN_E;
    int v[SCAN_E];
    int s = 0;
    #pragma unroll
    for (int i = 0; i < SCAN_E; ++i) {
        v[i] = (base + i < N_NODES) ? deg[base + i] : 0;
        s += v[i];
    }
    lds[t] = s;
    __syncthreads();
    for (int off = 1; off < SCAN_T; off <<= 1) {
        int val = lds[t];
        int add = (t >= off) ? lds[t - off] : 0;
        __syncthreads();
        lds[t] = val + add;
        __syncthreads();
    }
    if (t == SCAN_T - 1) blocksum[b] = lds[SCAN_T - 1];
    int run = (t == 0) ? 0 : lds[t - 1];
    #pragma unroll
    for (int i = 0; i < SCAN_E; ++i) {
        if (base + i < N_NODES) offsets[base + i] = run;
        run += v[i];
    }
}

__global__ __launch_bounds__(64) void scan2_kernel(
    const int* __restrict__ blocksum, int* __restrict__ blockoff)
{
    __shared__ int lds[64];
    int t = threadIdx.x;
    lds[t] = (t < NSCAN) ? blocksum[t] : 0;
    __syncthreads();
    for (int off = 1; off < 64; off <<= 1) {
        int val = lds[t];
        int add = (t >= off) ? lds[t - off] : 0;
        __syncthreads();
        lds[t] = val + add;
        __syncthreads();
    }
    if (t < NSCAN) blockoff[t] = (t == 0) ? 0 : lds[t - 1];
}

__global__ __launch_bounds__(256) void scan3_kernel(
    int* __restrict__ offsets, const int* __restrict__ blockoff,
    int* __restrict__ cursor)
{
    int i = blockIdx.x * blockDim.x + threadIdx.x;
    if (i < N_NODES) {
        int v = offsets[i] + blockoff[i / SCAN_CHUNK];
        offsets[i] = v;
        cursor[i] = v;
    }
    if (i == 0) offsets[N_NODES] = N_EDGES;
}

__global__ __launch_bounds__(256) void fill_kernel(
    const int* __restrict__ src_idx, const int* __restrict__ dst_idx,
    const float* __restrict__ ea, int* __restrict__ cursor,
    int2* __restrict__ csr)
{
    int e = blockIdx.x * blockDim.x + threadIdx.x;
    if (e >= N_EDGES) return;
    int s = src_idx[e];
    int d = dst_idx[e];
    float w = ea[e];
    int pos = atomicAdd(&cursor[d], 1);
    csr[pos] = make_int2(s, __float_as_int(w));
}

__global__ __launch_bounds__(256) void gather_kernel(
    const float* __restrict__ x, const int* __restrict__ offsets,
    const int2* __restrict__ csr, float* __restrict__ agg)
{
    int wid = (int)((blockIdx.x * blockDim.x + threadIdx.x) >> 6);
    if (wid >= N_NODES) return;
    int lane = threadIdx.x & 63;
    int beg = __builtin_amdgcn_readfirstlane(offsets[wid]);
    int end = __builtin_amdgcn_readfirstlane(offsets[wid + 1]);
    float acc0 = 0.f, acc1 = 0.f;
    int j = beg;
    for (; j + 1 < end; j += 2) {
        int2 a = csr[j];
        int2 b = csr[j + 1];
        acc0 = fmaf(__int_as_float(a.y), x[(size_t)a.x * 64 + lane], acc0);
        acc1 = fmaf(__int_as_float(b.y), x[(size_t)b.x * 64 + lane], acc1);
    }
    if (j < end) {
        int2 a = csr[j];
        acc0 = fmaf(__int_as_float(a.y), x[(size_t)a.x * 64 + lane], acc0);
    }
    agg[(size_t)wid * 64 + lane] = acc0 + acc1;
}

__global__ __launch_bounds__(256) void scatter_kernel(
    const float* __restrict__ x,
    const int* __restrict__ src_idx,
    const int* __restrict__ dst_idx,
    const float* __restrict__ ea,
    float* __restrict__ agg)
{
    long long gid = (long long)blockIdx.x * blockDim.x + threadIdx.x;
    if (gid >= (long long)N_EDGES * 16) return;
    int e = (int)(gid >> 4);
    int q = (int)(gid & 15);
    int s = src_idx[e];
    int d = dst_idx[e];
    float w = ea[e];
    float4 v = reinterpret_cast<const float4*>(x)[(size_t)s * 16 + q];
    float* out = agg + (size_t)d * 64 + q * 4;
    atomicAdd(out + 0, w * v.x);
    atomicAdd(out + 1, w * v.y);
    atomicAdd(out + 2, w * v.z);
    atomicAdd(out + 3, w * v.w);
}

// fallback dense (f32 agg/x inputs, in-place, split-precision) — tiers 2/3
__global__ __launch_bounds__(256) void dense_mfma_kernel(
    float* __restrict__ aggh,
    const float* __restrict__ x,
    const float* __restrict__ W_rel,
    const float* __restrict__ b_rel,
    const float* __restrict__ W_root)
{
    __shared__ unsigned int Bf[2][4][4][64][4];
    int tid = threadIdx.x;
    #pragma unroll
    for (int g = 0; g < 8; ++g) {
        int q = tid * 8 + g;
        int i4   = (q & 1) * 4;
        int lane = (q >> 1) & 63;
        int dt   = (q >> 7) & 3;
        int kt   = (q >> 9) & 3;
        int d = dt * 16 + (lane & 15);
        int k = kt * 32 + (lane >> 4) * 8 + i4;
        const float* Wsrc = (k < 64) ? (W_rel + d * 64 + k)
                                     : (W_root + d * 64 + (k - 64));
        float4 w = *reinterpret_cast<const float4*>(Wsrc);
        float wf[4] = {w.x, w.y, w.z, w.w};
        unsigned int hi[4], lo[4];
        #pragma unroll
        for (int j = 0; j < 4; ++j) {
            unsigned int bits = __float_as_uint(wf[j]);
            hi[j] = bits >> 16;
            float resid = wf[j] - __uint_as_float(bits & 0xFFFF0000u);
            lo[j] = __float_as_uint(resid) >> 16;
        }
        int u = i4 >> 1;
        Bf[0][kt][dt][lane][u]     = hi[0] | (hi[1] << 16);
        Bf[0][kt][dt][lane][u + 1] = hi[2] | (hi[3] << 16);
        Bf[1][kt][dt][lane][u]     = lo[0] | (lo[1] << 16);
        Bf[1][kt][dt][lane][u + 1] = lo[2] | (lo[3] << 16);
    }
    __syncthreads();

    int wid = tid >> 6, lane = tid & 63;
    int nbase = blockIdx.x * DB + wid * 32;
    int r = lane & 15;
    int k0 = (lane >> 4) * 8;

    f32x4 acc[2][4];
    #pragma unroll
    for (int nt = 0; nt < 2; ++nt)
        #pragma unroll
        for (int dt = 0; dt < 4; ++dt)
            acc[nt][dt] = (f32x4){0.f, 0.f, 0.f, 0.f};

    #pragma unroll 1
    for (int kt = 0; kt < 4; ++kt) {
        bf16x8 bh[4], bl[4];
        #pragma unroll
        for (int dt = 0; dt < 4; ++dt) {
            bh[dt] = *reinterpret_cast<const bf16x8*>(&Bf[0][kt][dt][lane][0]);
            bl[dt] = *reinterpret_cast<const bf16x8*>(&Bf[1][kt][dt][lane][0]);
        }
        int kk = kt * 32 + k0;
        #pragma unroll
        for (int nt = 0; nt < 2; ++nt) {
            int node = nbase + nt * 16 + r;
            float av[8];
            if (node < N_NODES) {
                const float* srcrow = (kk < 64)
                    ? (aggh + (size_t)node * 64 + kk)
                    : (x + (size_t)node * 64 + (kk - 64));
                float4 v0 = reinterpret_cast<const float4*>(srcrow)[0];
                float4 v1 = reinterpret_cast<const float4*>(srcrow)[1];
                av[0] = v0.x; av[1] = v0.y; av[2] = v0.z; av[3] = v0.w;
                av[4] = v1.x; av[5] = v1.y; av[6] = v1.z; av[7] = v1.w;
            } else {
                #pragma unroll
                for (int i = 0; i < 8; ++i) av[i] = 0.f;
            }
            bf16x8 ah, al;
            #pragma unroll
            for (int i = 0; i < 8; ++i) {
                unsigned int bits = __float_as_uint(av[i]);
                ah[i] = (short)(bits >> 16);
                float resid = av[i] - __uint_as_float(bits & 0xFFFF0000u);
                al[i] = (short)(__float_as_uint(resid) >> 16);
            }
            #pragma unroll
            for (int dt = 0; dt < 4; ++dt) {
                acc[nt][dt] = __builtin_amdgcn_mfma_f32_16x16x32_bf16(ah, bh[dt], acc[nt][dt], 0, 0, 0);
                acc[nt][dt] = __builtin_amdgcn_mfma_f32_16x16x32_bf16(al, bh[dt], acc[nt][dt], 0, 0, 0);
                acc[nt][dt] = __builtin_amdgcn_mfma_f32_16x16x32_bf16(ah, bl[dt], acc[nt][dt], 0, 0, 0);
            }
        }
    }

    int rowg = (lane >> 4) * 4;
    #pragma unroll
    for (int dt = 0; dt < 4; ++dt) {
        int d = dt * 16 + r;
        float bias = b_rel[d];
        #pragma unroll
        for (int nt = 0; nt < 2; ++nt) {
            #pragma unroll
            for (int reg = 0; reg < 4; ++reg) {
                int node = nbase + nt * 16 + rowg + reg;
                if (node < N_NODES) {
                    float v = fmaxf(acc[nt][dt][reg] + bias, 0.f);
                    aggh[(size_t)node * 64 + d] = v;
                }
            }
        }
    }
}

#define NPW2 32
__global__ __launch_bounds__(256) void stats_kernel(
    const float* __restrict__ h,
    const int* __restrict__ batch,
    float* __restrict__ gsum,
    float* __restrict__ gsum2,
    float* __restrict__ gcnt)
{
    int wave = (int)((blockIdx.x * blockDim.x + threadIdx.x) >> 6);
    int lane = threadIdx.x & 63;
    int base = wave * NPW2;
    if (base >= N_NODES) return;
    int end = min(base + NPW2, N_NODES);

    int gcur = batch[base];
    float s = 0.f, s2 = 0.f, cnt = 0.f;
    for (int n = base; n < end; ++n) {
        int g = batch[n];
        if (g != gcur) {
            atomicAdd(&gsum[gcur * 64 + lane], s);
            atomicAdd(&gsum2[gcur * 64 + lane], s2);
            if (lane == 0) atomicAdd(&gcnt[gcur], cnt);
            s = 0.f; s2 = 0.f; cnt = 0.f;
            gcur = g;
        }
        float v = h[(size_t)n * 64 + lane];
        s += v;
        s2 = fmaf(v, v, s2);
        cnt += 1.f;
    }
    atomicAdd(&gsum[gcur * 64 + lane], s);
    atomicAdd(&gsum2[gcur * 64 + lane], s2);
    if (lane == 0) atomicAdd(&gcnt[gcur], cnt);
}

__global__ __launch_bounds__(256) void apply_kernel(
    const float* __restrict__ h,
    const int* __restrict__ batch,
    const float* __restrict__ Ag,
    const float* __restrict__ Bg,
    float* __restrict__ out)
{
    long long gid = (long long)blockIdx.x * blockDim.x + threadIdx.x;
    if (gid >= (long long)N_NODES * 16) return;
    int n = (int)(gid >> 4);
    int q = (int)(gid & 15);
    int g = batch[n];
    float4 hv = reinterpret_cast<const float4*>(h)[gid];
    float4 A = reinterpret_cast<const float4*>(Ag)[g * 16 + q];
    float4 B = reinterpret_cast<const float4*>(Bg)[g * 16 + q];
    float4 o;
    o.x = fmaf(A.x, hv.x, B.x);
    o.y = fmaf(A.y, hv.y, B.y);
    o.z = fmaf(A.z, hv.z, B.z);
    o.w = fmaf(A.w, hv.w, B.w);
    reinterpret_cast<float4*>(out)[gid] = o;
}

// ===========================================================================
extern "C" void kernel_launch(void* const* d_in, const int* in_sizes, int n_in,
                              void* d_out, int out_size, void* d_ws, size_t ws_size,
                              hipStream_t stream)
{
    const float* x      = (const float*)d_in[0];
    const int*   ei     = (const int*)d_in[1];
    const float* ea     = (const float*)d_in[2];
    const int*   batch  = (const int*)d_in[3];
    const float* W_rel  = (const float*)d_in[4];
    const float* b_rel  = (const float*)d_in[5];
    const float* W_root = (const float*)d_in[6];
    const float* gn_w   = (const float*)d_in[7];
    const float* gn_b   = (const float*)d_in[8];
    const float* gn_ms  = (const float*)d_in[9];
    const int* src_idx = ei;
    const int* dst_idx = ei + N_EDGES;

    char* wsp = (char*)d_ws;

    // ---------------- tier-1 layout (fixed-capacity buckets) ----------------
    int*   bucket_cur  = (int*)wsp;                                   // 256
    float* gsumN       = (float*)(bucket_cur + 256);                  // G*64
    float* gsum2N      = gsumN + NUM_GRAPHS * 64;                     // G*64
    float* gcntN       = gsum2N + NUM_GRAPHS * 64;                    // 64
    int2*  offsets2    = (int2*)(gcntN + 64);                         // N int2
    size_t regA_off    = (((size_t)((char*)(offsets2 + N_NODES) - wsp)) + 15) & ~(size_t)15;
    size_t binned_sz   = (size_t)NBUCKETS * BCAP * 8;
    size_t hbuf_sz     = (size_t)N_NODES * 64 * 2;
    size_t regA_sz     = (binned_sz > hbuf_sz ? binned_sz : hbuf_sz);
    unsigned long long* binned = (unsigned long long*)(wsp + regA_off);
    ushort* hbuf16     = (ushort*)(wsp + regA_off);
    unsigned int* csrN = (unsigned int*)(wsp + regA_off + regA_sz);   // NBUCKETS*BCAP*4B
    ushort* aggN       = (ushort*)((char*)csrN + (size_t)NBUCKETS * BCAP * 4);
    float*  AgN        = (float*)(aggN + (size_t)N_NODES * 64);
    float*  BgN        = AgN + NUM_GRAPHS * 64;
    ushort* xh         = (ushort*)(BgN + NUM_GRAPHS * 64);
    size_t reqN        = (size_t)((char*)(xh + (size_t)N_NODES * 64) - wsp);

    // ---------------- legacy layouts (tiers 2/3) ----------------
    int*   degL     = (int*)wsp;
    float* gsumL    = (float*)(degL + N_NODES);
    float* gsum2L   = gsumL + NUM_GRAPHS * 64;
    float* gcntL    = gsum2L + NUM_GRAPHS * 64;
    size_t zeroL    = ((size_t)N_NODES + 2 * NUM_GRAPHS * 64 + 64) * 4;
    int*   offsetsL = (int*)(gcntL + 64);
    int*   blocksum = offsetsL + N_NODES + 1;
    int*   blockoff = blocksum + 64;
    int*   cursorL  = blockoff + 64;
    size_t csrL_off = (((size_t)((char*)(cursorL + N_NODES) - wsp)) + 15) & ~(size_t)15;
    int2*  csrL     = (int2*)(wsp + csrL_off);
    float* aggL     = (float*)(csrL + N_EDGES);
    float* AgL      = aggL + (size_t)N_NODES * 64;
    float* BgL      = AgL + NUM_GRAPHS * 64;
    size_t reqL     = (size_t)((char*)(BgL + NUM_GRAPHS * 64) - wsp);

    if (ws_size >= reqN) {
        // ---------- tier 1 (8 launches) ----------
        xcast_init_kernel<<<XB + 16, 256, 0, stream>>>(
            x, xh, bucket_cur, gsumN, gsum2N, gcntN);
        binA_kernel<<<NBLK_A, A_THREADS, 0, stream>>>(src_idx, dst_idx, ea, bucket_cur, binned);
        binB_kernel<<<NBUCKETS, 256, 0, stream>>>(binned, bucket_cur, offsets2, csrN);
        gatherh_kernel<<<(N_NODES + 3) / 4, 256, 0, stream>>>(xh, offsets2, csrN, aggN);
        dense_mfma16_kernel<<<(N_NODES + DB - 1) / DB, 256, 0, stream>>>(
            aggN, xh, hbuf16, W_rel, b_rel, W_root);
        {
            int waves = (N_NODES + NPW - 1) / NPW;
            stats16_kernel<<<(waves + 3) / 4, 256, 0, stream>>>(hbuf16, batch, gsumN, gsum2N, gcntN);
        }
        finalize_kernel<<<(NUM_GRAPHS * 64 + 255) / 256, 256, 0, stream>>>(
            gsumN, gsum2N, gcntN, gn_w, gn_b, gn_ms, AgN, BgN);
        apply16_kernel<<<(N_NODES * 8 + 255) / 256, 256, 0, stream>>>(
            hbuf16, batch, AgN, BgN, (float*)d_out);
    } else if (ws_size >= reqL) {
        // ---------- tier 2: legacy CSR (f32) ----------
        hipMemsetAsync(d_ws, 0, zeroL, stream);
        hist_kernel<<<(N_EDGES + 255) / 256, 256, 0, stream>>>(dst_idx, degL);
        scan1_kernel<<<NSCAN, SCAN_T, 0, stream>>>(degL, offsetsL, blocksum);
        scan2_kernel<<<1, 64, 0, stream>>>(blocksum, blockoff);
        scan3_kernel<<<(N_NODES + 255) / 256, 256, 0, stream>>>(offsetsL, blockoff, cursorL);
        fill_kernel<<<(N_EDGES + 255) / 256, 256, 0, stream>>>(src_idx, dst_idx, ea, cursorL, csrL);
        gather_kernel<<<(N_NODES + 3) / 4, 256, 0, stream>>>(x, offsetsL, csrL, aggL);
        dense_mfma_kernel<<<(N_NODES + DB - 1) / DB, 256, 0, stream>>>(
            aggL, x, W_rel, b_rel, W_root);
        {
            int waves = (N_NODES + NPW2 - 1) / NPW2;
            stats_kernel<<<(waves + 3) / 4, 256, 0, stream>>>(aggL, batch, gsumL, gsum2L, gcntL);
        }
        finalize_kernel<<<(NUM_GRAPHS * 64 + 255) / 256, 256, 0, stream>>>(
            gsumL, gsum2L, gcntL, gn_w, gn_b, gn_ms, AgL, BgL);
        {
            long long total = (long long)N_NODES * 16;
            apply_kernel<<<(int)((total + 255) / 256), 256, 0, stream>>>(
                aggL, batch, AgL, BgL, (float*)d_out);
        }
    } else {
        // ---------- tier 3: atomic scatter ----------
        float* agg = (float*)(gcntL + 64);
        float* Ag  = agg + (size_t)N_NODES * 64;
        float* Bg  = Ag + NUM_GRAPHS * 64;
        size_t zb = zeroL + (size_t)N_NODES * 64 * 4;
        hipMemsetAsync(d_ws, 0, zb, stream);
        long long total = (long long)N_EDGES * 16;
        scatter_kernel<<<(int)((total + 255) / 256), 256, 0, stream>>>(
            x, src_idx, dst_idx, ea, agg);
        dense_mfma_kernel<<<(N_NODES + DB - 1) / DB, 256, 0, stream>>>(
            agg, x, W_rel, b_rel, W_root);
        {
            int waves = (N_NODES + NPW2 - 1) / NPW2;
            stats_kernel<<<(waves + 3) / 4, 256, 0, stream>>>(agg, batch, gsumL, gsum2L, gcntL);
        }
        finalize_kernel<<<(NUM_GRAPHS * 64 + 255) / 256, 256, 0, stream>>>(
            gsumL, gsum2L, gcntL, gn_w, gn_b, gn_ms, Ag, Bg);
        {
            long long t2 = (long long)N_NODES * 16;
            apply_kernel<<<(int)((t2 + 255) / 256), 256, 0, stream>>>(
                agg, batch, Ag, Bg, (float*)d_out);
        }
    }
}

// Round 14
// 144.986 us; speedup vs baseline: 1.3731x; 1.0534x over previous
//
#include <hip/hip_runtime.h>

#define N_NODES 100000
#define N_EDGES 1600000
#define D 64
#define NUM_GRAPHS 64
#define EPS 1e-5f

// ---- bucketed CSR build params ----
#define BSHIFT 9
#define NPB 512
#define NBUCKETS ((N_NODES + NPB - 1) / NPB)      // 196
#define BCAP 12288                                 // fixed bucket capacity
#define A_THREADS 1024
#define A_EPT 8
#define A_CHUNK (A_THREADS * A_EPT)               // 8192
#define NBLK_A ((N_EDGES + A_CHUNK - 1) / A_CHUNK) // 196
#define XB ((N_NODES * 64 / 8 + 255) / 256)       // xcast blocks (3125)

// ---- legacy scan params (fallback path) ----
#define SCAN_T 256
#define SCAN_E 8
#define SCAN_CHUNK (SCAN_T * SCAN_E)
#define NSCAN ((N_NODES + SCAN_CHUNK - 1) / SCAN_CHUNK)

typedef float f32x4 __attribute__((ext_vector_type(4)));
typedef short bf16x8 __attribute__((ext_vector_type(8)));

__device__ __forceinline__ ushort f32_to_bf16_rne(float v) {
    unsigned int bits = __float_as_uint(v);
    return (ushort)((bits + 0x7FFFu + ((bits >> 16) & 1u)) >> 16);
}
__device__ __forceinline__ float bf16lo_to_f32(unsigned int u) {
    return __uint_as_float(u << 16);
}
__device__ __forceinline__ float bf16hi_to_f32(unsigned int u) {
    return __uint_as_float(u & 0xFFFF0000u);
}

// ===========================================================================
// fused: blocks [0,XB) cast x->bf16; blocks [XB,XB+16) init cursors + stats
// ===========================================================================
__global__ __launch_bounds__(256) void xcast_init_kernel(
    const float* __restrict__ x, ushort* __restrict__ xh,
    int* __restrict__ bucket_cur, float* __restrict__ gsum,
    float* __restrict__ gsum2, float* __restrict__ gcnt)
{
    if (blockIdx.x < XB) {
        int i = blockIdx.x * blockDim.x + threadIdx.x;
        if (i >= N_NODES * 64 / 8) return;
        const float4* src = reinterpret_cast<const float4*>(x) + (size_t)i * 2;
        float4 v0 = src[0], v1 = src[1];
        float vf[8] = {v0.x, v0.y, v0.z, v0.w, v1.x, v1.y, v1.z, v1.w};
        union { ushort us[8]; uint4 u4; } o;
        #pragma unroll
        for (int j = 0; j < 8; ++j) o.us[j] = f32_to_bf16_rne(vf[j]);
        reinterpret_cast<uint4*>(xh)[i] = o.u4;
    } else {
        int i = (blockIdx.x - XB) * 256 + threadIdx.x;
        if (i < 256) bucket_cur[i] = i * BCAP;
        if (i < NUM_GRAPHS * 64) { gsum[i] = 0.f; gsum2[i] = 0.f; }
        if (i < 64) gcnt[i] = 0.f;
    }
}

// ===========================================================================
// bin edges into fixed-capacity bucket regions.
// packed 8B: lo = src | (dst&511)<<17 ; hi = w f32 bits
// ===========================================================================
__global__ __launch_bounds__(A_THREADS) void binA_kernel(
    const int* __restrict__ src_idx, const int* __restrict__ dst_idx,
    const float* __restrict__ ea, int* __restrict__ bucket_cursor,
    unsigned long long* __restrict__ binned)
{
    __shared__ int hist[NBUCKETS];
    __shared__ int lbase[NBUCKETS];
    int tid = threadIdx.x;
    if (tid < NBUCKETS) hist[tid] = 0;
    __syncthreads();

    int base = blockIdx.x * A_CHUNK;
    int srcv[A_EPT], dstv[A_EPT];
    float wv[A_EPT];
    #pragma unroll
    for (int i = 0; i < A_EPT; ++i) {
        int e = base + i * A_THREADS + tid;
        if (e < N_EDGES) {
            srcv[i] = src_idx[e];
            dstv[i] = dst_idx[e];
            wv[i]   = ea[e];
            atomicAdd(&hist[dstv[i] >> BSHIFT], 1);
        } else {
            dstv[i] = -1; srcv[i] = 0; wv[i] = 0.f;
        }
    }
    __syncthreads();
    if (tid < NBUCKETS) lbase[tid] = atomicAdd(&bucket_cursor[tid], hist[tid]);
    __syncthreads();
    if (tid < NBUCKETS) hist[tid] = 0;
    __syncthreads();
    #pragma unroll
    for (int i = 0; i < A_EPT; ++i) {
        if (dstv[i] >= 0) {
            int b = dstv[i] >> BSHIFT;
            int r = atomicAdd(&hist[b], 1);
            unsigned int lo = (unsigned int)(srcv[i] | ((dstv[i] & (NPB - 1)) << 17));
            unsigned long long pv = (unsigned long long)lo |
                ((unsigned long long)__float_as_uint(wv[i]) << 32);
            binned[lbase[b] + r] = pv;
        }
    }
}

// ===========================================================================
// per-bucket counting sort -> offsets2[] (int2 beg,end) + packed 4B csr[]
// ===========================================================================
__global__ __launch_bounds__(256) void binB_kernel(
    const unsigned long long* __restrict__ binned,
    const int* __restrict__ bucket_cur,
    int2* __restrict__ offsets2, unsigned int* __restrict__ csr)
{
    __shared__ int dcnt[NPB];
    __shared__ int doff[NPB];
    __shared__ int psum[256];
    int tid = threadIdx.x;
    int b = blockIdx.x;
    int beg = b * BCAP;
    int n = bucket_cur[b] - beg;

    for (int i = tid; i < NPB; i += 256) dcnt[i] = 0;
    __syncthreads();
    for (int j = tid; j < n; j += 256) {
        unsigned long long pv = binned[beg + j];
        atomicAdd(&dcnt[((unsigned int)pv) >> 17], 1);
    }
    __syncthreads();
    int e0 = dcnt[2 * tid], e1 = dcnt[2 * tid + 1];
    psum[tid] = e0 + e1;
    __syncthreads();
    for (int off = 1; off < 256; off <<= 1) {
        int v = psum[tid];
        int a = (tid >= off) ? psum[tid - off] : 0;
        __syncthreads();
        psum[tid] = v + a;
        __syncthreads();
    }
    int ex = (tid == 0) ? 0 : psum[tid - 1];
    doff[2 * tid] = ex;
    doff[2 * tid + 1] = ex + e0;
    __syncthreads();
    for (int i = tid; i < NPB; i += 256) {
        int node = (b << BSHIFT) + i;
        if (node < N_NODES) {
            int s = beg + doff[i];
            int e = beg + ((i + 1 < NPB) ? doff[i + 1] : n);
            offsets2[node] = make_int2(s, e);
        }
        dcnt[i] = doff[i];
    }
    __syncthreads();
    for (int j = tid; j < n; j += 256) {
        unsigned long long pv = binned[beg + j];
        unsigned int lo = (unsigned int)pv;
        unsigned int wbits = (unsigned int)(pv >> 32);
        int dlo = lo >> 17;
        int r = atomicAdd(&dcnt[dlo], 1);
        unsigned int field = ((wbits + 0x7FFFu + ((wbits >> 16) & 1u)) >> 16) & 0x7FFFu;
        csr[beg + r] = (lo & 0x1FFFFu) | (field << 17);
    }
}

// ===========================================================================
// Gather-aggregate v2: 4 nodes/wave, 16 lanes/node, 4 dims/lane (uint2 loads).
// One wave-wide VMEM serves 4 edges -> ~4x fewer issue slots than wave/node.
// ===========================================================================
__global__ __launch_bounds__(256) void gatherh4_kernel(
    const ushort* __restrict__ xh, const int2* __restrict__ offsets2,
    const unsigned int* __restrict__ csr, ushort* __restrict__ agg)
{
    int tid = threadIdx.x;
    int wave = tid >> 6, lane = tid & 63;
    int grp = lane >> 4, sl = lane & 15;
    int node = blockIdx.x * 16 + wave * 4 + grp;
    bool ok = (node < N_NODES);
    int2 o2 = ok ? offsets2[node] : make_int2(0, 0);
    int beg = o2.x, end = o2.y;

    float a0 = 0.f, a1 = 0.f, a2 = 0.f, a3 = 0.f;   // e0 stream
    float b0 = 0.f, b1 = 0.f, b2 = 0.f, b3 = 0.f;   // e1 stream
    int j = beg;
    for (; j + 1 < end; j += 2) {
        unsigned int e0 = csr[j];
        unsigned int e1 = csr[j + 1];
        uint2 x0 = *reinterpret_cast<const uint2*>(
            xh + (size_t)(e0 & 0x1FFFFu) * 64 + sl * 4);
        uint2 x1 = *reinterpret_cast<const uint2*>(
            xh + (size_t)(e1 & 0x1FFFFu) * 64 + sl * 4);
        float w0 = __uint_as_float((e0 >> 17) << 16);
        float w1 = __uint_as_float((e1 >> 17) << 16);
        a0 = fmaf(w0, bf16lo_to_f32(x0.x & 0xFFFFu), a0);
        a1 = fmaf(w0, bf16hi_to_f32(x0.x), a1);
        a2 = fmaf(w0, bf16lo_to_f32(x0.y & 0xFFFFu), a2);
        a3 = fmaf(w0, bf16hi_to_f32(x0.y), a3);
        b0 = fmaf(w1, bf16lo_to_f32(x1.x & 0xFFFFu), b0);
        b1 = fmaf(w1, bf16hi_to_f32(x1.x), b1);
        b2 = fmaf(w1, bf16lo_to_f32(x1.y & 0xFFFFu), b2);
        b3 = fmaf(w1, bf16hi_to_f32(x1.y), b3);
    }
    if (j < end) {
        unsigned int e0 = csr[j];
        uint2 x0 = *reinterpret_cast<const uint2*>(
            xh + (size_t)(e0 & 0x1FFFFu) * 64 + sl * 4);
        float w0 = __uint_as_float((e0 >> 17) << 16);
        a0 = fmaf(w0, bf16lo_to_f32(x0.x & 0xFFFFu), a0);
        a1 = fmaf(w0, bf16hi_to_f32(x0.x), a1);
        a2 = fmaf(w0, bf16lo_to_f32(x0.y & 0xFFFFu), a2);
        a3 = fmaf(w0, bf16hi_to_f32(x0.y), a3);
    }
    if (ok) {
        unsigned int lo = (unsigned int)f32_to_bf16_rne(a0 + b0)
                        | ((unsigned int)f32_to_bf16_rne(a1 + b1) << 16);
        unsigned int hi = (unsigned int)f32_to_bf16_rne(a2 + b2)
                        | ((unsigned int)f32_to_bf16_rne(a3 + b3) << 16);
        *reinterpret_cast<uint2*>(agg + (size_t)node * 64 + sl * 4) =
            make_uint2(lo, hi);
    }
}

// ===========================================================================
// Dense (MFMA, plain bf16 inputs): h = relu([agg|x] @ [W^T] + b) -> bf16
// ===========================================================================
#define DB 128
__global__ __launch_bounds__(256) void dense_mfma16_kernel(
    const ushort* __restrict__ agg, const ushort* __restrict__ xh,
    ushort* __restrict__ hout,
    const float* __restrict__ W_rel, const float* __restrict__ b_rel,
    const float* __restrict__ W_root)
{
    __shared__ unsigned int Bf[4][4][64][4];   // 16 KB
    int tid = threadIdx.x;

    #pragma unroll
    for (int g = 0; g < 8; ++g) {
        int q = tid * 8 + g;
        int i4   = (q & 1) * 4;
        int lane = (q >> 1) & 63;
        int dt   = (q >> 7) & 3;
        int kt   = (q >> 9) & 3;
        int d = dt * 16 + (lane & 15);
        int k = kt * 32 + (lane >> 4) * 8 + i4;
        const float* Wsrc = (k < 64) ? (W_rel + d * 64 + k)
                                     : (W_root + d * 64 + (k - 64));
        float4 w = *reinterpret_cast<const float4*>(Wsrc);
        unsigned int b0 = f32_to_bf16_rne(w.x);
        unsigned int b1 = f32_to_bf16_rne(w.y);
        unsigned int b2 = f32_to_bf16_rne(w.z);
        unsigned int b3 = f32_to_bf16_rne(w.w);
        int u = i4 >> 1;
        Bf[kt][dt][lane][u]     = b0 | (b1 << 16);
        Bf[kt][dt][lane][u + 1] = b2 | (b3 << 16);
    }
    __syncthreads();

    int wid = tid >> 6, lane = tid & 63;
    int nbase = blockIdx.x * DB + wid * 32;
    int r = lane & 15;
    int k0 = (lane >> 4) * 8;

    f32x4 acc[2][4];
    #pragma unroll
    for (int nt = 0; nt < 2; ++nt)
        #pragma unroll
        for (int dt = 0; dt < 4; ++dt)
            acc[nt][dt] = (f32x4){0.f, 0.f, 0.f, 0.f};

    bf16x8 zf;
    #pragma unroll
    for (int i = 0; i < 8; ++i) zf[i] = 0;

    #pragma unroll 1
    for (int kt = 0; kt < 4; ++kt) {
        bf16x8 bh[4];
        #pragma unroll
        for (int dt = 0; dt < 4; ++dt)
            bh[dt] = *reinterpret_cast<const bf16x8*>(&Bf[kt][dt][lane][0]);
        int kk = kt * 32 + k0;
        #pragma unroll
        for (int nt = 0; nt < 2; ++nt) {
            int node = nbase + nt * 16 + r;
            bool ok = (node < N_NODES);
            const ushort* srcrow = (kk < 64)
                ? (agg + (size_t)node * 64 + kk)
                : (xh + (size_t)node * 64 + (kk - 64));
            bf16x8 a = ok ? *reinterpret_cast<const bf16x8*>(srcrow) : zf;
            #pragma unroll
            for (int dt = 0; dt < 4; ++dt)
                acc[nt][dt] = __builtin_amdgcn_mfma_f32_16x16x32_bf16(a, bh[dt], acc[nt][dt], 0, 0, 0);
        }
    }

    int rowg = (lane >> 4) * 4;
    #pragma unroll
    for (int dt = 0; dt < 4; ++dt) {
        int d = dt * 16 + r;
        float bias = b_rel[d];
        #pragma unroll
        for (int nt = 0; nt < 2; ++nt) {
            #pragma unroll
            for (int reg = 0; reg < 4; ++reg) {
                int node = nbase + nt * 16 + rowg + reg;
                if (node < N_NODES) {
                    float v = fmaxf(acc[nt][dt][reg] + bias, 0.f);
                    hout[(size_t)node * 64 + d] = f32_to_bf16_rne(v);
                }
            }
        }
    }
}

// ===========================================================================
// stats (bf16 h): per-(graph, dim) sum, sum^2, count
// ===========================================================================
#define NPW 32
__global__ __launch_bounds__(256) void stats16_kernel(
    const ushort* __restrict__ h,
    const int* __restrict__ batch,
    float* __restrict__ gsum,
    float* __restrict__ gsum2,
    float* __restrict__ gcnt)
{
    int wave = (int)((blockIdx.x * blockDim.x + threadIdx.x) >> 6);
    int lane = threadIdx.x & 63;
    int base = wave * NPW;
    if (base >= N_NODES) return;
    int end = min(base + NPW, N_NODES);

    int gcur = batch[base];
    float s = 0.f, s2 = 0.f, cnt = 0.f;
    for (int n = base; n < end; ++n) {
        int g = batch[n];
        if (g != gcur) {
            atomicAdd(&gsum[gcur * 64 + lane], s);
            atomicAdd(&gsum2[gcur * 64 + lane], s2);
            if (lane == 0) atomicAdd(&gcnt[gcur], cnt);
            s = 0.f; s2 = 0.f; cnt = 0.f;
            gcur = g;
        }
        float v = __uint_as_float((unsigned int)h[(size_t)n * 64 + lane] << 16);
        s += v;
        s2 = fmaf(v, v, s2);
        cnt += 1.f;
    }
    atomicAdd(&gsum[gcur * 64 + lane], s);
    atomicAdd(&gsum2[gcur * 64 + lane], s2);
    if (lane == 0) atomicAdd(&gcnt[gcur], cnt);
}

// ===========================================================================
// finalize: fold stats into per-(g,d) affine A,B
// ===========================================================================
__global__ __launch_bounds__(256) void finalize_kernel(
    const float* __restrict__ gsum,
    const float* __restrict__ gsum2,
    const float* __restrict__ gcnt,
    const float* __restrict__ gn_w,
    const float* __restrict__ gn_b,
    const float* __restrict__ gn_ms,
    float* __restrict__ Ag,
    float* __restrict__ Bg)
{
    int i = blockIdx.x * blockDim.x + threadIdx.x;
    if (i >= NUM_GRAPHS * 64) return;
    int g = i >> 6, d = i & 63;
    float c = fmaxf(gcnt[g], 1.f);
    float m = gsum[i] / c;
    float q = gsum2[i] / c;
    float s = gn_ms[d];
    float var = q - (2.f * s - s * s) * m * m;
    float inv = rsqrtf(fmaxf(var, 0.f) + EPS);
    float A = gn_w[d] * inv;
    Ag[i] = A;
    Bg[i] = gn_b[d] - A * s * m;
}

// ===========================================================================
// apply (bf16 h): out[n][d] = A[g][d]*h[n][d] + B[g][d]; 8 dims/thread
// ===========================================================================
__global__ __launch_bounds__(256) void apply16_kernel(
    const ushort* __restrict__ h,
    const int* __restrict__ batch,
    const float* __restrict__ Ag,
    const float* __restrict__ Bg,
    float* __restrict__ out)
{
    int i = blockIdx.x * blockDim.x + threadIdx.x;
    if (i >= N_NODES * 8) return;
    int n = i >> 3;
    int q = i & 7;
    int g = batch[n];
    union { uint4 u4; ushort us[8]; } hv;
    hv.u4 = *reinterpret_cast<const uint4*>(h + (size_t)n * 64 + q * 8);
    const float4* Av = reinterpret_cast<const float4*>(Ag + g * 64 + q * 8);
    const float4* Bv = reinterpret_cast<const float4*>(Bg + g * 64 + q * 8);
    float4 A0 = Av[0], A1 = Av[1];
    float4 B0 = Bv[0], B1 = Bv[1];
    float Af[8] = {A0.x, A0.y, A0.z, A0.w, A1.x, A1.y, A1.z, A1.w};
    float Bf_[8] = {B0.x, B0.y, B0.z, B0.w, B1.x, B1.y, B1.z, B1.w};
    float4 o0, o1;
    float of[8];
    #pragma unroll
    for (int j = 0; j < 8; ++j) {
        float v = __uint_as_float((unsigned int)hv.us[j] << 16);
        of[j] = fmaf(Af[j], v, Bf_[j]);
    }
    o0.x = of[0]; o0.y = of[1]; o0.z = of[2]; o0.w = of[3];
    o1.x = of[4]; o1.y = of[5]; o1.z = of[6]; o1.w = of[7];
    float4* op = reinterpret_cast<float4*>(out + (size_t)n * 64 + q * 8);
    op[0] = o0;
    op[1] = o1;
}

// ===========================================================================
// LEGACY PATH (fallback tiers, f32 h)
// ===========================================================================
__global__ __launch_bounds__(256) void hist_kernel(
    const int* __restrict__ dst_idx, int* __restrict__ deg)
{
    int e = blockIdx.x * blockDim.x + threadIdx.x;
    if (e >= N_EDGES) return;
    atomicAdd(&deg[dst_idx[e]], 1);
}

__global__ __launch_bounds__(SCAN_T) void scan1_kernel(
    const int* __restrict__ deg, int* __restrict__ offsets,
    int* __restrict__ blocksum)
{
    __shared__ int lds[SCAN_T];
    int b = blockIdx.x, t = threadIdx.x;
    int base = b * SCAN_CHUNK + t * SCAN_E;
    int v[SCAN_E];
    int s = 0;
    #pragma unroll
    for (int i = 0; i < SCAN_E; ++i) {
        v[i] = (base + i < N_NODES) ? deg[base + i] : 0;
        s += v[i];
    }
    lds[t] = s;
    __syncthreads();
    for (int off = 1; off < SCAN_T; off <<= 1) {
        int val = lds[t];
        int add = (t >= off) ? lds[t - off] : 0;
        __syncthreads();
        lds[t] = val + add;
        __syncthreads();
    }
    if (t == SCAN_T - 1) blocksum[b] = lds[SCAN_T - 1];
    int run = (t == 0) ? 0 : lds[t - 1];
    #pragma unroll
    for (int i = 0; i < SCAN_E; ++i) {
        if (base + i < N_NODES) offsets[base + i] = run;
        run += v[i];
    }
}

__global__ __launch_bounds__(64) void scan2_kernel(
    const int* __restrict__ blocksum, int* __restrict__ blockoff)
{
    __shared__ int lds[64];
    int t = threadIdx.x;
    lds[t] = (t < NSCAN) ? blocksum[t] : 0;
    __syncthreads();
    for (int off = 1; off < 64; off <<= 1) {
        int val = lds[t];
        int add = (t >= off) ? lds[t - off] : 0;
        __syncthreads();
        lds[t] = val + add;
        __syncthreads();
    }
    if (t < NSCAN) blockoff[t] = (t == 0) ? 0 : lds[t - 1];
}

__global__ __launch_bounds__(256) void scan3_kernel(
    int* __restrict__ offsets, const int* __restrict__ blockoff,
    int* __restrict__ cursor)
{
    int i = blockIdx.x * blockDim.x + threadIdx.x;
    if (i < N_NODES) {
        int v = offsets[i] + blockoff[i / SCAN_CHUNK];
        offsets[i] = v;
        cursor[i] = v;
    }
    if (i == 0) offsets[N_NODES] = N_EDGES;
}

__global__ __launch_bounds__(256) void fill_kernel(
    const int* __restrict__ src_idx, const int* __restrict__ dst_idx,
    const float* __restrict__ ea, int* __restrict__ cursor,
    int2* __restrict__ csr)
{
    int e = blockIdx.x * blockDim.x + threadIdx.x;
    if (e >= N_EDGES) return;
    int s = src_idx[e];
    int d = dst_idx[e];
    float w = ea[e];
    int pos = atomicAdd(&cursor[d], 1);
    csr[pos] = make_int2(s, __float_as_int(w));
}

__global__ __launch_bounds__(256) void gather_kernel(
    const float* __restrict__ x, const int* __restrict__ offsets,
    const int2* __restrict__ csr, float* __restrict__ agg)
{
    int wid = (int)((blockIdx.x * blockDim.x + threadIdx.x) >> 6);
    if (wid >= N_NODES) return;
    int lane = threadIdx.x & 63;
    int beg = __builtin_amdgcn_readfirstlane(offsets[wid]);
    int end = __builtin_amdgcn_readfirstlane(offsets[wid + 1]);
    float acc0 = 0.f, acc1 = 0.f;
    int j = beg;
    for (; j + 1 < end; j += 2) {
        int2 a = csr[j];
        int2 b = csr[j + 1];
        acc0 = fmaf(__int_as_float(a.y), x[(size_t)a.x * 64 + lane], acc0);
        acc1 = fmaf(__int_as_float(b.y), x[(size_t)b.x * 64 + lane], acc1);
    }
    if (j < end) {
        int2 a = csr[j];
        acc0 = fmaf(__int_as_float(a.y), x[(size_t)a.x * 64 + lane], acc0);
    }
    agg[(size_t)wid * 64 + lane] = acc0 + acc1;
}

__global__ __launch_bounds__(256) void scatter_kernel(
    const float* __restrict__ x,
    const int* __restrict__ src_idx,
    const int* __restrict__ dst_idx,
    const float* __restrict__ ea,
    float* __restrict__ agg)
{
    long long gid = (long long)blockIdx.x * blockDim.x + threadIdx.x;
    if (gid >= (long long)N_EDGES * 16) return;
    int e = (int)(gid >> 4);
    int q = (int)(gid & 15);
    int s = src_idx[e];
    int d = dst_idx[e];
    float w = ea[e];
    float4 v = reinterpret_cast<const float4*>(x)[(size_t)s * 16 + q];
    float* out = agg + (size_t)d * 64 + q * 4;
    atomicAdd(out + 0, w * v.x);
    atomicAdd(out + 1, w * v.y);
    atomicAdd(out + 2, w * v.z);
    atomicAdd(out + 3, w * v.w);
}

// fallback dense (f32 agg/x inputs, in-place, split-precision) — tiers 2/3
__global__ __launch_bounds__(256) void dense_mfma_kernel(
    float* __restrict__ aggh,
    const float* __restrict__ x,
    const float* __restrict__ W_rel,
    const float* __restrict__ b_rel,
    const float* __restrict__ W_root)
{
    __shared__ unsigned int Bf[2][4][4][64][4];
    int tid = threadIdx.x;
    #pragma unroll
    for (int g = 0; g < 8; ++g) {
        int q = tid * 8 + g;
        int i4   = (q & 1) * 4;
        int lane = (q >> 1) & 63;
        int dt   = (q >> 7) & 3;
        int kt   = (q >> 9) & 3;
        int d = dt * 16 + (lane & 15);
        int k = kt * 32 + (lane >> 4) * 8 + i4;
        const float* Wsrc = (k < 64) ? (W_rel + d * 64 + k)
                                     : (W_root + d * 64 + (k - 64));
        float4 w = *reinterpret_cast<const float4*>(Wsrc);
        float wf[4] = {w.x, w.y, w.z, w.w};
        unsigned int hi[4], lo[4];
        #pragma unroll
        for (int j = 0; j < 4; ++j) {
            unsigned int bits = __float_as_uint(wf[j]);
            hi[j] = bits >> 16;
            float resid = wf[j] - __uint_as_float(bits & 0xFFFF0000u);
            lo[j] = __float_as_uint(resid) >> 16;
        }
        int u = i4 >> 1;
        Bf[0][kt][dt][lane][u]     = hi[0] | (hi[1] << 16);
        Bf[0][kt][dt][lane][u + 1] = hi[2] | (hi[3] << 16);
        Bf[1][kt][dt][lane][u]     = lo[0] | (lo[1] << 16);
        Bf[1][kt][dt][lane][u + 1] = lo[2] | (lo[3] << 16);
    }
    __syncthreads();

    int wid = tid >> 6, lane = tid & 63;
    int nbase = blockIdx.x * DB + wid * 32;
    int r = lane & 15;
    int k0 = (lane >> 4) * 8;

    f32x4 acc[2][4];
    #pragma unroll
    for (int nt = 0; nt < 2; ++nt)
        #pragma unroll
        for (int dt = 0; dt < 4; ++dt)
            acc[nt][dt] = (f32x4){0.f, 0.f, 0.f, 0.f};

    #pragma unroll 1
    for (int kt = 0; kt < 4; ++kt) {
        bf16x8 bh[4], bl[4];
        #pragma unroll
        for (int dt = 0; dt < 4; ++dt) {
            bh[dt] = *reinterpret_cast<const bf16x8*>(&Bf[0][kt][dt][lane][0]);
            bl[dt] = *reinterpret_cast<const bf16x8*>(&Bf[1][kt][dt][lane][0]);
        }
        int kk = kt * 32 + k0;
        #pragma unroll
        for (int nt = 0; nt < 2; ++nt) {
            int node = nbase + nt * 16 + r;
            float av[8];
            if (node < N_NODES) {
                const float* srcrow = (kk < 64)
                    ? (aggh + (size_t)node * 64 + kk)
                    : (x + (size_t)node * 64 + (kk - 64));
                float4 v0 = reinterpret_cast<const float4*>(srcrow)[0];
                float4 v1 = reinterpret_cast<const float4*>(srcrow)[1];
                av[0] = v0.x; av[1] = v0.y; av[2] = v0.z; av[3] = v0.w;
                av[4] = v1.x; av[5] = v1.y; av[6] = v1.z; av[7] = v1.w;
            } else {
                #pragma unroll
                for (int i = 0; i < 8; ++i) av[i] = 0.f;
            }
            bf16x8 ah, al;
            #pragma unroll
            for (int i = 0; i < 8; ++i) {
                unsigned int bits = __float_as_uint(av[i]);
                ah[i] = (short)(bits >> 16);
                float resid = av[i] - __uint_as_float(bits & 0xFFFF0000u);
                al[i] = (short)(__float_as_uint(resid) >> 16);
            }
            #pragma unroll
            for (int dt = 0; dt < 4; ++dt) {
                acc[nt][dt] = __builtin_amdgcn_mfma_f32_16x16x32_bf16(ah, bh[dt], acc[nt][dt], 0, 0, 0);
                acc[nt][dt] = __builtin_amdgcn_mfma_f32_16x16x32_bf16(al, bh[dt], acc[nt][dt], 0, 0, 0);
                acc[nt][dt] = __builtin_amdgcn_mfma_f32_16x16x32_bf16(ah, bl[dt], acc[nt][dt], 0, 0, 0);
            }
        }
    }

    int rowg = (lane >> 4) * 4;
    #pragma unroll
    for (int dt = 0; dt < 4; ++dt) {
        int d = dt * 16 + r;
        float bias = b_rel[d];
        #pragma unroll
        for (int nt = 0; nt < 2; ++nt) {
            #pragma unroll
            for (int reg = 0; reg < 4; ++reg) {
                int node = nbase + nt * 16 + rowg + reg;
                if (node < N_NODES) {
                    float v = fmaxf(acc[nt][dt][reg] + bias, 0.f);
                    aggh[(size_t)node * 64 + d] = v;
                }
            }
        }
    }
}

#define NPW2 32
__global__ __launch_bounds__(256) void stats_kernel(
    const float* __restrict__ h,
    const int* __restrict__ batch,
    float* __restrict__ gsum,
    float* __restrict__ gsum2,
    float* __restrict__ gcnt)
{
    int wave = (int)((blockIdx.x * blockDim.x + threadIdx.x) >> 6);
    int lane = threadIdx.x & 63;
    int base = wave * NPW2;
    if (base >= N_NODES) return;
    int end = min(base + NPW2, N_NODES);

    int gcur = batch[base];
    float s = 0.f, s2 = 0.f, cnt = 0.f;
    for (int n = base; n < end; ++n) {
        int g = batch[n];
        if (g != gcur) {
            atomicAdd(&gsum[gcur * 64 + lane], s);
            atomicAdd(&gsum2[gcur * 64 + lane], s2);
            if (lane == 0) atomicAdd(&gcnt[gcur], cnt);
            s = 0.f; s2 = 0.f; cnt = 0.f;
            gcur = g;
        }
        float v = h[(size_t)n * 64 + lane];
        s += v;
        s2 = fmaf(v, v, s2);
        cnt += 1.f;
    }
    atomicAdd(&gsum[gcur * 64 + lane], s);
    atomicAdd(&gsum2[gcur * 64 + lane], s2);
    if (lane == 0) atomicAdd(&gcnt[gcur], cnt);
}

__global__ __launch_bounds__(256) void apply_kernel(
    const float* __restrict__ h,
    const int* __restrict__ batch,
    const float* __restrict__ Ag,
    const float* __restrict__ Bg,
    float* __restrict__ out)
{
    long long gid = (long long)blockIdx.x * blockDim.x + threadIdx.x;
    if (gid >= (long long)N_NODES * 16) return;
    int n = (int)(gid >> 4);
    int q = (int)(gid & 15);
    int g = batch[n];
    float4 hv = reinterpret_cast<const float4*>(h)[gid];
    float4 A = reinterpret_cast<const float4*>(Ag)[g * 16 + q];
    float4 B = reinterpret_cast<const float4*>(Bg)[g * 16 + q];
    float4 o;
    o.x = fmaf(A.x, hv.x, B.x);
    o.y = fmaf(A.y, hv.y, B.y);
    o.z = fmaf(A.z, hv.z, B.z);
    o.w = fmaf(A.w, hv.w, B.w);
    reinterpret_cast<float4*>(out)[gid] = o;
}

// ===========================================================================
extern "C" void kernel_launch(void* const* d_in, const int* in_sizes, int n_in,
                              void* d_out, int out_size, void* d_ws, size_t ws_size,
                              hipStream_t stream)
{
    const float* x      = (const float*)d_in[0];
    const int*   ei     = (const int*)d_in[1];
    const float* ea     = (const float*)d_in[2];
    const int*   batch  = (const int*)d_in[3];
    const float* W_rel  = (const float*)d_in[4];
    const float* b_rel  = (const float*)d_in[5];
    const float* W_root = (const float*)d_in[6];
    const float* gn_w   = (const float*)d_in[7];
    const float* gn_b   = (const float*)d_in[8];
    const float* gn_ms  = (const float*)d_in[9];
    const int* src_idx = ei;
    const int* dst_idx = ei + N_EDGES;

    char* wsp = (char*)d_ws;

    // ---------------- tier-1 layout (fixed-capacity buckets) ----------------
    int*   bucket_cur  = (int*)wsp;                                   // 256
    float* gsumN       = (float*)(bucket_cur + 256);                  // G*64
    float* gsum2N      = gsumN + NUM_GRAPHS * 64;                     // G*64
    float* gcntN       = gsum2N + NUM_GRAPHS * 64;                    // 64
    int2*  offsets2    = (int2*)(gcntN + 64);                         // N int2
    size_t regA_off    = (((size_t)((char*)(offsets2 + N_NODES) - wsp)) + 15) & ~(size_t)15;
    size_t binned_sz   = (size_t)NBUCKETS * BCAP * 8;
    size_t hbuf_sz     = (size_t)N_NODES * 64 * 2;
    size_t regA_sz     = (binned_sz > hbuf_sz ? binned_sz : hbuf_sz);
    unsigned long long* binned = (unsigned long long*)(wsp + regA_off);
    ushort* hbuf16     = (ushort*)(wsp + regA_off);
    unsigned int* csrN = (unsigned int*)(wsp + regA_off + regA_sz);   // NBUCKETS*BCAP*4B
    ushort* aggN       = (ushort*)((char*)csrN + (size_t)NBUCKETS * BCAP * 4);
    float*  AgN        = (float*)(aggN + (size_t)N_NODES * 64);
    float*  BgN        = AgN + NUM_GRAPHS * 64;
    ushort* xh         = (ushort*)(BgN + NUM_GRAPHS * 64);
    size_t reqN        = (size_t)((char*)(xh + (size_t)N_NODES * 64) - wsp);

    // ---------------- legacy layouts (tiers 2/3) ----------------
    int*   degL     = (int*)wsp;
    float* gsumL    = (float*)(degL + N_NODES);
    float* gsum2L   = gsumL + NUM_GRAPHS * 64;
    float* gcntL    = gsum2L + NUM_GRAPHS * 64;
    size_t zeroL    = ((size_t)N_NODES + 2 * NUM_GRAPHS * 64 + 64) * 4;
    int*   offsetsL = (int*)(gcntL + 64);
    int*   blocksum = offsetsL + N_NODES + 1;
    int*   blockoff = blocksum + 64;
    int*   cursorL  = blockoff + 64;
    size_t csrL_off = (((size_t)((char*)(cursorL + N_NODES) - wsp)) + 15) & ~(size_t)15;
    int2*  csrL     = (int2*)(wsp + csrL_off);
    float* aggL     = (float*)(csrL + N_EDGES);
    float* AgL      = aggL + (size_t)N_NODES * 64;
    float* BgL      = AgL + NUM_GRAPHS * 64;
    size_t reqL     = (size_t)((char*)(BgL + NUM_GRAPHS * 64) - wsp);

    if (ws_size >= reqN) {
        // ---------- tier 1 (8 launches) ----------
        xcast_init_kernel<<<XB + 16, 256, 0, stream>>>(
            x, xh, bucket_cur, gsumN, gsum2N, gcntN);
        binA_kernel<<<NBLK_A, A_THREADS, 0, stream>>>(src_idx, dst_idx, ea, bucket_cur, binned);
        binB_kernel<<<NBUCKETS, 256, 0, stream>>>(binned, bucket_cur, offsets2, csrN);
        gatherh4_kernel<<<(N_NODES + 15) / 16, 256, 0, stream>>>(xh, offsets2, csrN, aggN);
        dense_mfma16_kernel<<<(N_NODES + DB - 1) / DB, 256, 0, stream>>>(
            aggN, xh, hbuf16, W_rel, b_rel, W_root);
        {
            int waves = (N_NODES + NPW - 1) / NPW;
            stats16_kernel<<<(waves + 3) / 4, 256, 0, stream>>>(hbuf16, batch, gsumN, gsum2N, gcntN);
        }
        finalize_kernel<<<(NUM_GRAPHS * 64 + 255) / 256, 256, 0, stream>>>(
            gsumN, gsum2N, gcntN, gn_w, gn_b, gn_ms, AgN, BgN);
        apply16_kernel<<<(N_NODES * 8 + 255) / 256, 256, 0, stream>>>(
            hbuf16, batch, AgN, BgN, (float*)d_out);
    } else if (ws_size >= reqL) {
        // ---------- tier 2: legacy CSR (f32) ----------
        hipMemsetAsync(d_ws, 0, zeroL, stream);
        hist_kernel<<<(N_EDGES + 255) / 256, 256, 0, stream>>>(dst_idx, degL);
        scan1_kernel<<<NSCAN, SCAN_T, 0, stream>>>(degL, offsetsL, blocksum);
        scan2_kernel<<<1, 64, 0, stream>>>(blocksum, blockoff);
        scan3_kernel<<<(N_NODES + 255) / 256, 256, 0, stream>>>(offsetsL, blockoff, cursorL);
        fill_kernel<<<(N_EDGES + 255) / 256, 256, 0, stream>>>(src_idx, dst_idx, ea, cursorL, csrL);
        gather_kernel<<<(N_NODES + 3) / 4, 256, 0, stream>>>(x, offsetsL, csrL, aggL);
        dense_mfma_kernel<<<(N_NODES + DB - 1) / DB, 256, 0, stream>>>(
            aggL, x, W_rel, b_rel, W_root);
        {
            int waves = (N_NODES + NPW2 - 1) / NPW2;
            stats_kernel<<<(waves + 3) / 4, 256, 0, stream>>>(aggL, batch, gsumL, gsum2L, gcntL);
        }
        finalize_kernel<<<(NUM_GRAPHS * 64 + 255) / 256, 256, 0, stream>>>(
            gsumL, gsum2L, gcntL, gn_w, gn_b, gn_ms, AgL, BgL);
        {
            long long total = (long long)N_NODES * 16;
            apply_kernel<<<(int)((total + 255) / 256), 256, 0, stream>>>(
                aggL, batch, AgL, BgL, (float*)d_out);
        }
    } else {
        // ---------- tier 3: atomic scatter ----------
        float* agg = (float*)(gcntL + 64);
        float* Ag  = agg + (size_t)N_NODES * 64;
        float* Bg  = Ag + NUM_GRAPHS * 64;
        size_t zb = zeroL + (size_t)N_NODES * 64 * 4;
        hipMemsetAsync(d_ws, 0, zb, stream);
        long long total = (long long)N_EDGES * 16;
        scatter_kernel<<<(int)((total + 255) / 256), 256, 0, stream>>>(
            x, src_idx, dst_idx, ea, agg);
        dense_mfma_kernel<<<(N_NODES + DB - 1) / DB, 256, 0, stream>>>(
            agg, x, W_rel, b_rel, W_root);
        {
            int waves = (N_NODES + NPW2 - 1) / NPW2;
            stats_kernel<<<(waves + 3) / 4, 256, 0, stream>>>(agg, batch, gsumL, gsum2L, gcntL);
        }
        finalize_kernel<<<(NUM_GRAPHS * 64 + 255) / 256, 256, 0, stream>>>(
            gsumL, gsum2L, gcntL, gn_w, gn_b, gn_ms, Ag, Bg);
        {
            long long t2 = (long long)N_NODES * 16;
            apply_kernel<<<(int)((t2 + 255) / 256), 256, 0, stream>>>(
                agg, batch, Ag, Bg, (float*)d_out);
        }
    }
}

// Round 15
// 142.736 us; speedup vs baseline: 1.3947x; 1.0158x over previous
//
#include <hip/hip_runtime.h>

#define N_NODES 100000
#define N_EDGES 1600000
#define D 64
#define NUM_GRAPHS 64
#define EPS 1e-5f

// ---- bucketed CSR build params ----
#define BSHIFT 9
#define NPB 512
#define NBUCKETS ((N_NODES + NPB - 1) / NPB)      // 196
#define BCAP 12288                                 // fixed bucket capacity
#define A_THREADS 1024
#define A_EPT 4
#define A_CHUNK (A_THREADS * A_EPT)               // 4096
#define NBLK_A ((N_EDGES + A_CHUNK - 1) / A_CHUNK) // 391
#define XB ((N_NODES * 64 / 8 + 255) / 256)       // xcast blocks (3125)

// ---- legacy scan params (fallback path) ----
#define SCAN_T 256
#define SCAN_E 8
#define SCAN_CHUNK (SCAN_T * SCAN_E)
#define NSCAN ((N_NODES + SCAN_CHUNK - 1) / SCAN_CHUNK)

typedef float f32x4 __attribute__((ext_vector_type(4)));
typedef short bf16x8 __attribute__((ext_vector_type(8)));

__device__ __forceinline__ ushort f32_to_bf16_rne(float v) {
    unsigned int bits = __float_as_uint(v);
    return (ushort)((bits + 0x7FFFu + ((bits >> 16) & 1u)) >> 16);
}
__device__ __forceinline__ float bf16lo_to_f32(unsigned int u) {
    return __uint_as_float(u << 16);
}
__device__ __forceinline__ float bf16hi_to_f32(unsigned int u) {
    return __uint_as_float(u & 0xFFFF0000u);
}

// ===========================================================================
// fused: blocks [0,XB) cast x->bf16; blocks [XB,XB+16) init cursors + stats
// ===========================================================================
__global__ __launch_bounds__(256) void xcast_init_kernel(
    const float* __restrict__ x, ushort* __restrict__ xh,
    int* __restrict__ bucket_cur, float* __restrict__ gsum,
    float* __restrict__ gsum2, float* __restrict__ gcnt)
{
    if (blockIdx.x < XB) {
        int i = blockIdx.x * blockDim.x + threadIdx.x;
        if (i >= N_NODES * 64 / 8) return;
        const float4* src = reinterpret_cast<const float4*>(x) + (size_t)i * 2;
        float4 v0 = src[0], v1 = src[1];
        float vf[8] = {v0.x, v0.y, v0.z, v0.w, v1.x, v1.y, v1.z, v1.w};
        union { ushort us[8]; uint4 u4; } o;
        #pragma unroll
        for (int j = 0; j < 8; ++j) o.us[j] = f32_to_bf16_rne(vf[j]);
        reinterpret_cast<uint4*>(xh)[i] = o.u4;
    } else {
        int i = (blockIdx.x - XB) * 256 + threadIdx.x;
        if (i < 256) bucket_cur[i] = i * BCAP;
        if (i < NUM_GRAPHS * 64) { gsum[i] = 0.f; gsum2[i] = 0.f; }
        if (i < 64) gcnt[i] = 0.f;
    }
}

// ===========================================================================
// bin edges into fixed-capacity bucket regions. 391 blocks (full CU coverage)
// packed 8B: lo = src | (dst&511)<<17 ; hi = w f32 bits
// ===========================================================================
__global__ __launch_bounds__(A_THREADS) void binA_kernel(
    const int* __restrict__ src_idx, const int* __restrict__ dst_idx,
    const float* __restrict__ ea, int* __restrict__ bucket_cursor,
    unsigned long long* __restrict__ binned)
{
    __shared__ int hist[NBUCKETS];
    __shared__ int lbase[NBUCKETS];
    int tid = threadIdx.x;
    if (tid < NBUCKETS) hist[tid] = 0;
    __syncthreads();

    int base = blockIdx.x * A_CHUNK;
    int srcv[A_EPT], dstv[A_EPT];
    float wv[A_EPT];
    #pragma unroll
    for (int i = 0; i < A_EPT; ++i) {
        int e = base + i * A_THREADS + tid;
        if (e < N_EDGES) {
            srcv[i] = src_idx[e];
            dstv[i] = dst_idx[e];
            wv[i]   = ea[e];
            atomicAdd(&hist[dstv[i] >> BSHIFT], 1);
        } else {
            dstv[i] = -1; srcv[i] = 0; wv[i] = 0.f;
        }
    }
    __syncthreads();
    if (tid < NBUCKETS) lbase[tid] = atomicAdd(&bucket_cursor[tid], hist[tid]);
    __syncthreads();
    if (tid < NBUCKETS) hist[tid] = 0;
    __syncthreads();
    #pragma unroll
    for (int i = 0; i < A_EPT; ++i) {
        if (dstv[i] >= 0) {
            int b = dstv[i] >> BSHIFT;
            int r = atomicAdd(&hist[b], 1);
            unsigned int lo = (unsigned int)(srcv[i] | ((dstv[i] & (NPB - 1)) << 17));
            unsigned long long pv = (unsigned long long)lo |
                ((unsigned long long)__float_as_uint(wv[i]) << 32);
            binned[lbase[b] + r] = pv;
        }
    }
}

// ===========================================================================
// per-bucket counting sort -> offsets2[] (int2 beg,end) + packed 4B csr[]
// ===========================================================================
__global__ __launch_bounds__(256) void binB_kernel(
    const unsigned long long* __restrict__ binned,
    const int* __restrict__ bucket_cur,
    int2* __restrict__ offsets2, unsigned int* __restrict__ csr)
{
    __shared__ int dcnt[NPB];
    __shared__ int doff[NPB];
    __shared__ int psum[256];
    int tid = threadIdx.x;
    int b = blockIdx.x;
    int beg = b * BCAP;
    int n = bucket_cur[b] - beg;

    for (int i = tid; i < NPB; i += 256) dcnt[i] = 0;
    __syncthreads();
    for (int j = tid; j < n; j += 256) {
        unsigned long long pv = binned[beg + j];
        atomicAdd(&dcnt[((unsigned int)pv) >> 17], 1);
    }
    __syncthreads();
    int e0 = dcnt[2 * tid], e1 = dcnt[2 * tid + 1];
    psum[tid] = e0 + e1;
    __syncthreads();
    for (int off = 1; off < 256; off <<= 1) {
        int v = psum[tid];
        int a = (tid >= off) ? psum[tid - off] : 0;
        __syncthreads();
        psum[tid] = v + a;
        __syncthreads();
    }
    int ex = (tid == 0) ? 0 : psum[tid - 1];
    doff[2 * tid] = ex;
    doff[2 * tid + 1] = ex + e0;
    __syncthreads();
    for (int i = tid; i < NPB; i += 256) {
        int node = (b << BSHIFT) + i;
        if (node < N_NODES) {
            int s = beg + doff[i];
            int e = beg + ((i + 1 < NPB) ? doff[i + 1] : n);
            offsets2[node] = make_int2(s, e);
        }
        dcnt[i] = doff[i];
    }
    __syncthreads();
    for (int j = tid; j < n; j += 256) {
        unsigned long long pv = binned[beg + j];
        unsigned int lo = (unsigned int)pv;
        unsigned int wbits = (unsigned int)(pv >> 32);
        int dlo = lo >> 17;
        int r = atomicAdd(&dcnt[dlo], 1);
        unsigned int field = ((wbits + 0x7FFFu + ((wbits >> 16) & 1u)) >> 16) & 0x7FFFu;
        csr[beg + r] = (lo & 0x1FFFFu) | (field << 17);
    }
}

// ===========================================================================
// Gather-aggregate: 4 nodes/wave, 16 lanes/node, 4 dims/lane, 4-deep unroll.
// ===========================================================================
__global__ __launch_bounds__(256) void gatherh4_kernel(
    const ushort* __restrict__ xh, const int2* __restrict__ offsets2,
    const unsigned int* __restrict__ csr, ushort* __restrict__ agg)
{
    int tid = threadIdx.x;
    int wave = tid >> 6, lane = tid & 63;
    int grp = lane >> 4, sl = lane & 15;
    int node = blockIdx.x * 16 + wave * 4 + grp;
    bool ok = (node < N_NODES);
    int2 o2 = ok ? offsets2[node] : make_int2(0, 0);
    int beg = o2.x, end = o2.y;

    float acc[4][4];
    #pragma unroll
    for (int s = 0; s < 4; ++s)
        #pragma unroll
        for (int i = 0; i < 4; ++i) acc[s][i] = 0.f;

    int j = beg;
    for (; j + 3 < end; j += 4) {
        unsigned int e[4];
        #pragma unroll
        for (int u = 0; u < 4; ++u) e[u] = csr[j + u];
        uint2 xv[4];
        #pragma unroll
        for (int u = 0; u < 4; ++u)
            xv[u] = *reinterpret_cast<const uint2*>(
                xh + (size_t)(e[u] & 0x1FFFFu) * 64 + sl * 4);
        #pragma unroll
        for (int u = 0; u < 4; ++u) {
            float w = __uint_as_float((e[u] >> 17) << 16);
            acc[u][0] = fmaf(w, bf16lo_to_f32(xv[u].x & 0xFFFFu), acc[u][0]);
            acc[u][1] = fmaf(w, bf16hi_to_f32(xv[u].x), acc[u][1]);
            acc[u][2] = fmaf(w, bf16lo_to_f32(xv[u].y & 0xFFFFu), acc[u][2]);
            acc[u][3] = fmaf(w, bf16hi_to_f32(xv[u].y), acc[u][3]);
        }
    }
    for (; j < end; ++j) {
        unsigned int e0 = csr[j];
        uint2 x0 = *reinterpret_cast<const uint2*>(
            xh + (size_t)(e0 & 0x1FFFFu) * 64 + sl * 4);
        float w = __uint_as_float((e0 >> 17) << 16);
        acc[0][0] = fmaf(w, bf16lo_to_f32(x0.x & 0xFFFFu), acc[0][0]);
        acc[0][1] = fmaf(w, bf16hi_to_f32(x0.x), acc[0][1]);
        acc[0][2] = fmaf(w, bf16lo_to_f32(x0.y & 0xFFFFu), acc[0][2]);
        acc[0][3] = fmaf(w, bf16hi_to_f32(x0.y), acc[0][3]);
    }
    if (ok) {
        float r0 = (acc[0][0] + acc[1][0]) + (acc[2][0] + acc[3][0]);
        float r1 = (acc[0][1] + acc[1][1]) + (acc[2][1] + acc[3][1]);
        float r2 = (acc[0][2] + acc[1][2]) + (acc[2][2] + acc[3][2]);
        float r3 = (acc[0][3] + acc[1][3]) + (acc[2][3] + acc[3][3]);
        unsigned int lo = (unsigned int)f32_to_bf16_rne(r0)
                        | ((unsigned int)f32_to_bf16_rne(r1) << 16);
        unsigned int hi = (unsigned int)f32_to_bf16_rne(r2)
                        | ((unsigned int)f32_to_bf16_rne(r3) << 16);
        *reinterpret_cast<uint2*>(agg + (size_t)node * 64 + sl * 4) =
            make_uint2(lo, hi);
    }
}

// ===========================================================================
// Dense (MFMA, plain bf16 inputs): h = relu([agg|x] @ [W^T] + b) -> bf16
// ===========================================================================
#define DB 128
__global__ __launch_bounds__(256) void dense_mfma16_kernel(
    const ushort* __restrict__ agg, const ushort* __restrict__ xh,
    ushort* __restrict__ hout,
    const float* __restrict__ W_rel, const float* __restrict__ b_rel,
    const float* __restrict__ W_root)
{
    __shared__ unsigned int Bf[4][4][64][4];   // 16 KB
    int tid = threadIdx.x;

    #pragma unroll
    for (int g = 0; g < 8; ++g) {
        int q = tid * 8 + g;
        int i4   = (q & 1) * 4;
        int lane = (q >> 1) & 63;
        int dt   = (q >> 7) & 3;
        int kt   = (q >> 9) & 3;
        int d = dt * 16 + (lane & 15);
        int k = kt * 32 + (lane >> 4) * 8 + i4;
        const float* Wsrc = (k < 64) ? (W_rel + d * 64 + k)
                                     : (W_root + d * 64 + (k - 64));
        float4 w = *reinterpret_cast<const float4*>(Wsrc);
        unsigned int b0 = f32_to_bf16_rne(w.x);
        unsigned int b1 = f32_to_bf16_rne(w.y);
        unsigned int b2 = f32_to_bf16_rne(w.z);
        unsigned int b3 = f32_to_bf16_rne(w.w);
        int u = i4 >> 1;
        Bf[kt][dt][lane][u]     = b0 | (b1 << 16);
        Bf[kt][dt][lane][u + 1] = b2 | (b3 << 16);
    }
    __syncthreads();

    int wid = tid >> 6, lane = tid & 63;
    int nbase = blockIdx.x * DB + wid * 32;
    int r = lane & 15;
    int k0 = (lane >> 4) * 8;

    f32x4 acc[2][4];
    #pragma unroll
    for (int nt = 0; nt < 2; ++nt)
        #pragma unroll
        for (int dt = 0; dt < 4; ++dt)
            acc[nt][dt] = (f32x4){0.f, 0.f, 0.f, 0.f};

    bf16x8 zf;
    #pragma unroll
    for (int i = 0; i < 8; ++i) zf[i] = 0;

    #pragma unroll 1
    for (int kt = 0; kt < 4; ++kt) {
        bf16x8 bh[4];
        #pragma unroll
        for (int dt = 0; dt < 4; ++dt)
            bh[dt] = *reinterpret_cast<const bf16x8*>(&Bf[kt][dt][lane][0]);
        int kk = kt * 32 + k0;
        #pragma unroll
        for (int nt = 0; nt < 2; ++nt) {
            int node = nbase + nt * 16 + r;
            bool ok = (node < N_NODES);
            const ushort* srcrow = (kk < 64)
                ? (agg + (size_t)node * 64 + kk)
                : (xh + (size_t)node * 64 + (kk - 64));
            bf16x8 a = ok ? *reinterpret_cast<const bf16x8*>(srcrow) : zf;
            #pragma unroll
            for (int dt = 0; dt < 4; ++dt)
                acc[nt][dt] = __builtin_amdgcn_mfma_f32_16x16x32_bf16(a, bh[dt], acc[nt][dt], 0, 0, 0);
        }
    }

    int rowg = (lane >> 4) * 4;
    #pragma unroll
    for (int dt = 0; dt < 4; ++dt) {
        int d = dt * 16 + r;
        float bias = b_rel[d];
        #pragma unroll
        for (int nt = 0; nt < 2; ++nt) {
            #pragma unroll
            for (int reg = 0; reg < 4; ++reg) {
                int node = nbase + nt * 16 + rowg + reg;
                if (node < N_NODES) {
                    float v = fmaxf(acc[nt][dt][reg] + bias, 0.f);
                    hout[(size_t)node * 64 + d] = f32_to_bf16_rne(v);
                }
            }
        }
    }
}

// ===========================================================================
// stats (bf16 h): per-(graph, dim) sum, sum^2, count
// ===========================================================================
#define NPW 32
__global__ __launch_bounds__(256) void stats16_kernel(
    const ushort* __restrict__ h,
    const int* __restrict__ batch,
    float* __restrict__ gsum,
    float* __restrict__ gsum2,
    float* __restrict__ gcnt)
{
    int wave = (int)((blockIdx.x * blockDim.x + threadIdx.x) >> 6);
    int lane = threadIdx.x & 63;
    int base = wave * NPW;
    if (base >= N_NODES) return;
    int end = min(base + NPW, N_NODES);

    int gcur = batch[base];
    float s = 0.f, s2 = 0.f, cnt = 0.f;
    for (int n = base; n < end; ++n) {
        int g = batch[n];
        if (g != gcur) {
            atomicAdd(&gsum[gcur * 64 + lane], s);
            atomicAdd(&gsum2[gcur * 64 + lane], s2);
            if (lane == 0) atomicAdd(&gcnt[gcur], cnt);
            s = 0.f; s2 = 0.f; cnt = 0.f;
            gcur = g;
        }
        float v = __uint_as_float((unsigned int)h[(size_t)n * 64 + lane] << 16);
        s += v;
        s2 = fmaf(v, v, s2);
        cnt += 1.f;
    }
    atomicAdd(&gsum[gcur * 64 + lane], s);
    atomicAdd(&gsum2[gcur * 64 + lane], s2);
    if (lane == 0) atomicAdd(&gcnt[gcur], cnt);
}

// ===========================================================================
// finalize: fold stats into per-(g,d) affine A,B
// ===========================================================================
__global__ __launch_bounds__(256) void finalize_kernel(
    const float* __restrict__ gsum,
    const float* __restrict__ gsum2,
    const float* __restrict__ gcnt,
    const float* __restrict__ gn_w,
    const float* __restrict__ gn_b,
    const float* __restrict__ gn_ms,
    float* __restrict__ Ag,
    float* __restrict__ Bg)
{
    int i = blockIdx.x * blockDim.x + threadIdx.x;
    if (i >= NUM_GRAPHS * 64) return;
    int g = i >> 6, d = i & 63;
    float c = fmaxf(gcnt[g], 1.f);
    float m = gsum[i] / c;
    float q = gsum2[i] / c;
    float s = gn_ms[d];
    float var = q - (2.f * s - s * s) * m * m;
    float inv = rsqrtf(fmaxf(var, 0.f) + EPS);
    float A = gn_w[d] * inv;
    Ag[i] = A;
    Bg[i] = gn_b[d] - A * s * m;
}

// ===========================================================================
// apply (bf16 h): out[n][d] = A[g][d]*h[n][d] + B[g][d]; 8 dims/thread
// ===========================================================================
__global__ __launch_bounds__(256) void apply16_kernel(
    const ushort* __restrict__ h,
    const int* __restrict__ batch,
    const float* __restrict__ Ag,
    const float* __restrict__ Bg,
    float* __restrict__ out)
{
    int i = blockIdx.x * blockDim.x + threadIdx.x;
    if (i >= N_NODES * 8) return;
    int n = i >> 3;
    int q = i & 7;
    int g = batch[n];
    union { uint4 u4; ushort us[8]; } hv;
    hv.u4 = *reinterpret_cast<const uint4*>(h + (size_t)n * 64 + q * 8);
    const float4* Av = reinterpret_cast<const float4*>(Ag + g * 64 + q * 8);
    const float4* Bv = reinterpret_cast<const float4*>(Bg + g * 64 + q * 8);
    float4 A0 = Av[0], A1 = Av[1];
    float4 B0 = Bv[0], B1 = Bv[1];
    float Af[8] = {A0.x, A0.y, A0.z, A0.w, A1.x, A1.y, A1.z, A1.w};
    float Bf_[8] = {B0.x, B0.y, B0.z, B0.w, B1.x, B1.y, B1.z, B1.w};
    float4 o0, o1;
    float of[8];
    #pragma unroll
    for (int j = 0; j < 8; ++j) {
        float v = __uint_as_float((unsigned int)hv.us[j] << 16);
        of[j] = fmaf(Af[j], v, Bf_[j]);
    }
    o0.x = of[0]; o0.y = of[1]; o0.z = of[2]; o0.w = of[3];
    o1.x = of[4]; o1.y = of[5]; o1.z = of[6]; o1.w = of[7];
    float4* op = reinterpret_cast<float4*>(out + (size_t)n * 64 + q * 8);
    op[0] = o0;
    op[1] = o1;
}

// ===========================================================================
// LEGACY PATH (fallback tiers, f32 h)
// ===========================================================================
__global__ __launch_bounds__(256) void hist_kernel(
    const int* __restrict__ dst_idx, int* __restrict__ deg)
{
    int e = blockIdx.x * blockDim.x + threadIdx.x;
    if (e >= N_EDGES) return;
    atomicAdd(&deg[dst_idx[e]], 1);
}

__global__ __launch_bounds__(SCAN_T) void scan1_kernel(
    const int* __restrict__ deg, int* __restrict__ offsets,
    int* __restrict__ blocksum)
{
    __shared__ int lds[SCAN_T];
    int b = blockIdx.x, t = threadIdx.x;
    int base = b * SCAN_CHUNK + t * SCAN_E;
    int v[SCAN_E];
    int s = 0;
    #pragma unroll
    for (int i = 0; i < SCAN_E; ++i) {
        v[i] = (base + i < N_NODES) ? deg[base + i] : 0;
        s += v[i];
    }
    lds[t] = s;
    __syncthreads();
    for (int off = 1; off < SCAN_T; off <<= 1) {
        int val = lds[t];
        int add = (t >= off) ? lds[t - off] : 0;
        __syncthreads();
        lds[t] = val + add;
        __syncthreads();
    }
    if (t == SCAN_T - 1) blocksum[b] = lds[SCAN_T - 1];
    int run = (t == 0) ? 0 : lds[t - 1];
    #pragma unroll
    for (int i = 0; i < SCAN_E; ++i) {
        if (base + i < N_NODES) offsets[base + i] = run;
        run += v[i];
    }
}

__global__ __launch_bounds__(64) void scan2_kernel(
    const int* __restrict__ blocksum, int* __restrict__ blockoff)
{
    __shared__ int lds[64];
    int t = threadIdx.x;
    lds[t] = (t < NSCAN) ? blocksum[t] : 0;
    __syncthreads();
    for (int off = 1; off < 64; off <<= 1) {
        int val = lds[t];
        int add = (t >= off) ? lds[t - off] : 0;
        __syncthreads();
        lds[t] = val + add;
        __syncthreads();
    }
    if (t < NSCAN) blockoff[t] = (t == 0) ? 0 : lds[t - 1];
}

__global__ __launch_bounds__(256) void scan3_kernel(
    int* __restrict__ offsets, const int* __restrict__ blockoff,
    int* __restrict__ cursor)
{
    int i = blockIdx.x * blockDim.x + threadIdx.x;
    if (i < N_NODES) {
        int v = offsets[i] + blockoff[i / SCAN_CHUNK];
        offsets[i] = v;
        cursor[i] = v;
    }
    if (i == 0) offsets[N_NODES] = N_EDGES;
}

__global__ __launch_bounds__(256) void fill_kernel(
    const int* __restrict__ src_idx, const int* __restrict__ dst_idx,
    const float* __restrict__ ea, int* __restrict__ cursor,
    int2* __restrict__ csr)
{
    int e = blockIdx.x * blockDim.x + threadIdx.x;
    if (e >= N_EDGES) return;
    int s = src_idx[e];
    int d = dst_idx[e];
    float w = ea[e];
    int pos = atomicAdd(&cursor[d], 1);
    csr[pos] = make_int2(s, __float_as_int(w));
}

__global__ __launch_bounds__(256) void gather_kernel(
    const float* __restrict__ x, const int* __restrict__ offsets,
    const int2* __restrict__ csr, float* __restrict__ agg)
{
    int wid = (int)((blockIdx.x * blockDim.x + threadIdx.x) >> 6);
    if (wid >= N_NODES) return;
    int lane = threadIdx.x & 63;
    int beg = __builtin_amdgcn_readfirstlane(offsets[wid]);
    int end = __builtin_amdgcn_readfirstlane(offsets[wid + 1]);
    float acc0 = 0.f, acc1 = 0.f;
    int j = beg;
    for (; j + 1 < end; j += 2) {
        int2 a = csr[j];
        int2 b = csr[j + 1];
        acc0 = fmaf(__int_as_float(a.y), x[(size_t)a.x * 64 + lane], acc0);
        acc1 = fmaf(__int_as_float(b.y), x[(size_t)b.x * 64 + lane], acc1);
    }
    if (j < end) {
        int2 a = csr[j];
        acc0 = fmaf(__int_as_float(a.y), x[(size_t)a.x * 64 + lane], acc0);
    }
    agg[(size_t)wid * 64 + lane] = acc0 + acc1;
}

__global__ __launch_bounds__(256) void scatter_kernel(
    const float* __restrict__ x,
    const int* __restrict__ src_idx,
    const int* __restrict__ dst_idx,
    const float* __restrict__ ea,
    float* __restrict__ agg)
{
    long long gid = (long long)blockIdx.x * blockDim.x + threadIdx.x;
    if (gid >= (long long)N_EDGES * 16) return;
    int e = (int)(gid >> 4);
    int q = (int)(gid & 15);
    int s = src_idx[e];
    int d = dst_idx[e];
    float w = ea[e];
    float4 v = reinterpret_cast<const float4*>(x)[(size_t)s * 16 + q];
    float* out = agg + (size_t)d * 64 + q * 4;
    atomicAdd(out + 0, w * v.x);
    atomicAdd(out + 1, w * v.y);
    atomicAdd(out + 2, w * v.z);
    atomicAdd(out + 3, w * v.w);
}

// fallback dense (f32 agg/x inputs, in-place, split-precision) — tiers 2/3
__global__ __launch_bounds__(256) void dense_mfma_kernel(
    float* __restrict__ aggh,
    const float* __restrict__ x,
    const float* __restrict__ W_rel,
    const float* __restrict__ b_rel,
    const float* __restrict__ W_root)
{
    __shared__ unsigned int Bf[2][4][4][64][4];
    int tid = threadIdx.x;
    #pragma unroll
    for (int g = 0; g < 8; ++g) {
        int q = tid * 8 + g;
        int i4   = (q & 1) * 4;
        int lane = (q >> 1) & 63;
        int dt   = (q >> 7) & 3;
        int kt   = (q >> 9) & 3;
        int d = dt * 16 + (lane & 15);
        int k = kt * 32 + (lane >> 4) * 8 + i4;
        const float* Wsrc = (k < 64) ? (W_rel + d * 64 + k)
                                     : (W_root + d * 64 + (k - 64));
        float4 w = *reinterpret_cast<const float4*>(Wsrc);
        float wf[4] = {w.x, w.y, w.z, w.w};
        unsigned int hi[4], lo[4];
        #pragma unroll
        for (int j = 0; j < 4; ++j) {
            unsigned int bits = __float_as_uint(wf[j]);
            hi[j] = bits >> 16;
            float resid = wf[j] - __uint_as_float(bits & 0xFFFF0000u);
            lo[j] = __float_as_uint(resid) >> 16;
        }
        int u = i4 >> 1;
        Bf[0][kt][dt][lane][u]     = hi[0] | (hi[1] << 16);
        Bf[0][kt][dt][lane][u + 1] = hi[2] | (hi[3] << 16);
        Bf[1][kt][dt][lane][u]     = lo[0] | (lo[1] << 16);
        Bf[1][kt][dt][lane][u + 1] = lo[2] | (lo[3] << 16);
    }
    __syncthreads();

    int wid = tid >> 6, lane = tid & 63;
    int nbase = blockIdx.x * DB + wid * 32;
    int r = lane & 15;
    int k0 = (lane >> 4) * 8;

    f32x4 acc[2][4];
    #pragma unroll
    for (int nt = 0; nt < 2; ++nt)
        #pragma unroll
        for (int dt = 0; dt < 4; ++dt)
            acc[nt][dt] = (f32x4){0.f, 0.f, 0.f, 0.f};

    #pragma unroll 1
    for (int kt = 0; kt < 4; ++kt) {
        bf16x8 bh[4], bl[4];
        #pragma unroll
        for (int dt = 0; dt < 4; ++dt) {
            bh[dt] = *reinterpret_cast<const bf16x8*>(&Bf[0][kt][dt][lane][0]);
            bl[dt] = *reinterpret_cast<const bf16x8*>(&Bf[1][kt][dt][lane][0]);
        }
        int kk = kt * 32 + k0;
        #pragma unroll
        for (int nt = 0; nt < 2; ++nt) {
            int node = nbase + nt * 16 + r;
            float av[8];
            if (node < N_NODES) {
                const float* srcrow = (kk < 64)
                    ? (aggh + (size_t)node * 64 + kk)
                    : (x + (size_t)node * 64 + (kk - 64));
                float4 v0 = reinterpret_cast<const float4*>(srcrow)[0];
                float4 v1 = reinterpret_cast<const float4*>(srcrow)[1];
                av[0] = v0.x; av[1] = v0.y; av[2] = v0.z; av[3] = v0.w;
                av[4] = v1.x; av[5] = v1.y; av[6] = v1.z; av[7] = v1.w;
            } else {
                #pragma unroll
                for (int i = 0; i < 8; ++i) av[i] = 0.f;
            }
            bf16x8 ah, al;
            #pragma unroll
            for (int i = 0; i < 8; ++i) {
                unsigned int bits = __float_as_uint(av[i]);
                ah[i] = (short)(bits >> 16);
                float resid = av[i] - __uint_as_float(bits & 0xFFFF0000u);
                al[i] = (short)(__float_as_uint(resid) >> 16);
            }
            #pragma unroll
            for (int dt = 0; dt < 4; ++dt) {
                acc[nt][dt] = __builtin_amdgcn_mfma_f32_16x16x32_bf16(ah, bh[dt], acc[nt][dt], 0, 0, 0);
                acc[nt][dt] = __builtin_amdgcn_mfma_f32_16x16x32_bf16(al, bh[dt], acc[nt][dt], 0, 0, 0);
                acc[nt][dt] = __builtin_amdgcn_mfma_f32_16x16x32_bf16(ah, bl[dt], acc[nt][dt], 0, 0, 0);
            }
        }
    }

    int rowg = (lane >> 4) * 4;
    #pragma unroll
    for (int dt = 0; dt < 4; ++dt) {
        int d = dt * 16 + r;
        float bias = b_rel[d];
        #pragma unroll
        for (int nt = 0; nt < 2; ++nt) {
            #pragma unroll
            for (int reg = 0; reg < 4; ++reg) {
                int node = nbase + nt * 16 + rowg + reg;
                if (node < N_NODES) {
                    float v = fmaxf(acc[nt][dt][reg] + bias, 0.f);
                    aggh[(size_t)node * 64 + d] = v;
                }
            }
        }
    }
}

#define NPW2 32
__global__ __launch_bounds__(256) void stats_kernel(
    const float* __restrict__ h,
    const int* __restrict__ batch,
    float* __restrict__ gsum,
    float* __restrict__ gsum2,
    float* __restrict__ gcnt)
{
    int wave = (int)((blockIdx.x * blockDim.x + threadIdx.x) >> 6);
    int lane = threadIdx.x & 63;
    int base = wave * NPW2;
    if (base >= N_NODES) return;
    int end = min(base + NPW2, N_NODES);

    int gcur = batch[base];
    float s = 0.f, s2 = 0.f, cnt = 0.f;
    for (int n = base; n < end; ++n) {
        int g = batch[n];
        if (g != gcur) {
            atomicAdd(&gsum[gcur * 64 + lane], s);
            atomicAdd(&gsum2[gcur * 64 + lane], s2);
            if (lane == 0) atomicAdd(&gcnt[gcur], cnt);
            s = 0.f; s2 = 0.f; cnt = 0.f;
            gcur = g;
        }
        float v = h[(size_t)n * 64 + lane];
        s += v;
        s2 = fmaf(v, v, s2);
        cnt += 1.f;
    }
    atomicAdd(&gsum[gcur * 64 + lane], s);
    atomicAdd(&gsum2[gcur * 64 + lane], s2);
    if (lane == 0) atomicAdd(&gcnt[gcur], cnt);
}

__global__ __launch_bounds__(256) void apply_kernel(
    const float* __restrict__ h,
    const int* __restrict__ batch,
    const float* __restrict__ Ag,
    const float* __restrict__ Bg,
    float* __restrict__ out)
{
    long long gid = (long long)blockIdx.x * blockDim.x + threadIdx.x;
    if (gid >= (long long)N_NODES * 16) return;
    int n = (int)(gid >> 4);
    int q = (int)(gid & 15);
    int g = batch[n];
    float4 hv = reinterpret_cast<const float4*>(h)[gid];
    float4 A = reinterpret_cast<const float4*>(Ag)[g * 16 + q];
    float4 B = reinterpret_cast<const float4*>(Bg)[g * 16 + q];
    float4 o;
    o.x = fmaf(A.x, hv.x, B.x);
    o.y = fmaf(A.y, hv.y, B.y);
    o.z = fmaf(A.z, hv.z, B.z);
    o.w = fmaf(A.w, hv.w, B.w);
    reinterpret_cast<float4*>(out)[gid] = o;
}

// ===========================================================================
extern "C" void kernel_launch(void* const* d_in, const int* in_sizes, int n_in,
                              void* d_out, int out_size, void* d_ws, size_t ws_size,
                              hipStream_t stream)
{
    const float* x      = (const float*)d_in[0];
    const int*   ei     = (const int*)d_in[1];
    const float* ea     = (const float*)d_in[2];
    const int*   batch  = (const int*)d_in[3];
    const float* W_rel  = (const float*)d_in[4];
    const float* b_rel  = (const float*)d_in[5];
    const float* W_root = (const float*)d_in[6];
    const float* gn_w   = (const float*)d_in[7];
    const float* gn_b   = (const float*)d_in[8];
    const float* gn_ms  = (const float*)d_in[9];
    const int* src_idx = ei;
    const int* dst_idx = ei + N_EDGES;

    char* wsp = (char*)d_ws;

    // ---------------- tier-1 layout (fixed-capacity buckets) ----------------
    int*   bucket_cur  = (int*)wsp;                                   // 256
    float* gsumN       = (float*)(bucket_cur + 256);                  // G*64
    float* gsum2N      = gsumN + NUM_GRAPHS * 64;                     // G*64
    float* gcntN       = gsum2N + NUM_GRAPHS * 64;                    // 64
    int2*  offsets2    = (int2*)(gcntN + 64);                         // N int2
    size_t regA_off    = (((size_t)((char*)(offsets2 + N_NODES) - wsp)) + 15) & ~(size_t)15;
    size_t binned_sz   = (size_t)NBUCKETS * BCAP * 8;
    size_t hbuf_sz     = (size_t)N_NODES * 64 * 2;
    size_t regA_sz     = (binned_sz > hbuf_sz ? binned_sz : hbuf_sz);
    unsigned long long* binned = (unsigned long long*)(wsp + regA_off);
    ushort* hbuf16     = (ushort*)(wsp + regA_off);
    unsigned int* csrN = (unsigned int*)(wsp + regA_off + regA_sz);   // NBUCKETS*BCAP*4B
    ushort* aggN       = (ushort*)((char*)csrN + (size_t)NBUCKETS * BCAP * 4);
    float*  AgN        = (float*)(aggN + (size_t)N_NODES * 64);
    float*  BgN        = AgN + NUM_GRAPHS * 64;
    ushort* xh         = (ushort*)(BgN + NUM_GRAPHS * 64);
    size_t reqN        = (size_t)((char*)(xh + (size_t)N_NODES * 64) - wsp);

    // ---------------- legacy layouts (tiers 2/3) ----------------
    int*   degL     = (int*)wsp;
    float* gsumL    = (float*)(degL + N_NODES);
    float* gsum2L   = gsumL + NUM_GRAPHS * 64;
    float* gcntL    = gsum2L + NUM_GRAPHS * 64;
    size_t zeroL    = ((size_t)N_NODES + 2 * NUM_GRAPHS * 64 + 64) * 4;
    int*   offsetsL = (int*)(gcntL + 64);
    int*   blocksum = offsetsL + N_NODES + 1;
    int*   blockoff = blocksum + 64;
    int*   cursorL  = blockoff + 64;
    size_t csrL_off = (((size_t)((char*)(cursorL + N_NODES) - wsp)) + 15) & ~(size_t)15;
    int2*  csrL     = (int2*)(wsp + csrL_off);
    float* aggL     = (float*)(csrL + N_EDGES);
    float* AgL      = aggL + (size_t)N_NODES * 64;
    float* BgL      = AgL + NUM_GRAPHS * 64;
    size_t reqL     = (size_t)((char*)(BgL + NUM_GRAPHS * 64) - wsp);

    if (ws_size >= reqN) {
        // ---------- tier 1 (8 launches) ----------
        xcast_init_kernel<<<XB + 16, 256, 0, stream>>>(
            x, xh, bucket_cur, gsumN, gsum2N, gcntN);
        binA_kernel<<<NBLK_A, A_THREADS, 0, stream>>>(src_idx, dst_idx, ea, bucket_cur, binned);
        binB_kernel<<<NBUCKETS, 256, 0, stream>>>(binned, bucket_cur, offsets2, csrN);
        gatherh4_kernel<<<(N_NODES + 15) / 16, 256, 0, stream>>>(xh, offsets2, csrN, aggN);
        dense_mfma16_kernel<<<(N_NODES + DB - 1) / DB, 256, 0, stream>>>(
            aggN, xh, hbuf16, W_rel, b_rel, W_root);
        {
            int waves = (N_NODES + NPW - 1) / NPW;
            stats16_kernel<<<(waves + 3) / 4, 256, 0, stream>>>(hbuf16, batch, gsumN, gsum2N, gcntN);
        }
        finalize_kernel<<<(NUM_GRAPHS * 64 + 255) / 256, 256, 0, stream>>>(
            gsumN, gsum2N, gcntN, gn_w, gn_b, gn_ms, AgN, BgN);
        apply16_kernel<<<(N_NODES * 8 + 255) / 256, 256, 0, stream>>>(
            hbuf16, batch, AgN, BgN, (float*)d_out);
    } else if (ws_size >= reqL) {
        // ---------- tier 2: legacy CSR (f32) ----------
        hipMemsetAsync(d_ws, 0, zeroL, stream);
        hist_kernel<<<(N_EDGES + 255) / 256, 256, 0, stream>>>(dst_idx, degL);
        scan1_kernel<<<NSCAN, SCAN_T, 0, stream>>>(degL, offsetsL, blocksum);
        scan2_kernel<<<1, 64, 0, stream>>>(blocksum, blockoff);
        scan3_kernel<<<(N_NODES + 255) / 256, 256, 0, stream>>>(offsetsL, blockoff, cursorL);
        fill_kernel<<<(N_EDGES + 255) / 256, 256, 0, stream>>>(src_idx, dst_idx, ea, cursorL, csrL);
        gather_kernel<<<(N_NODES + 3) / 4, 256, 0, stream>>>(x, offsetsL, csrL, aggL);
        dense_mfma_kernel<<<(N_NODES + DB - 1) / DB, 256, 0, stream>>>(
            aggL, x, W_rel, b_rel, W_root);
        {
            int waves = (N_NODES + NPW2 - 1) / NPW2;
            stats_kernel<<<(waves + 3) / 4, 256, 0, stream>>>(aggL, batch, gsumL, gsum2L, gcntL);
        }
        finalize_kernel<<<(NUM_GRAPHS * 64 + 255) / 256, 256, 0, stream>>>(
            gsumL, gsum2L, gcntL, gn_w, gn_b, gn_ms, AgL, BgL);
        {
            long long total = (long long)N_NODES * 16;
            apply_kernel<<<(int)((total + 255) / 256), 256, 0, stream>>>(
                aggL, batch, AgL, BgL, (float*)d_out);
        }
    } else {
        // ---------- tier 3: atomic scatter ----------
        float* agg = (float*)(gcntL + 64);
        float* Ag  = agg + (size_t)N_NODES * 64;
        float* Bg  = Ag + NUM_GRAPHS * 64;
        size_t zb = zeroL + (size_t)N_NODES * 64 * 4;
        hipMemsetAsync(d_ws, 0, zb, stream);
        long long total = (long long)N_EDGES * 16;
        scatter_kernel<<<(int)((total + 255) / 256), 256, 0, stream>>>(
            x, src_idx, dst_idx, ea, agg);
        dense_mfma_kernel<<<(N_NODES + DB - 1) / DB, 256, 0, stream>>>(
            agg, x, W_rel, b_rel, W_root);
        {
            int waves = (N_NODES + NPW2 - 1) / NPW2;
            stats_kernel<<<(waves + 3) / 4, 256, 0, stream>>>(agg, batch, gsumL, gsum2L, gcntL);
        }
        finalize_kernel<<<(NUM_GRAPHS * 64 + 255) / 256, 256, 0, stream>>>(
            gsumL, gsum2L, gcntL, gn_w, gn_b, gn_ms, Ag, Bg);
        {
            long long t2 = (long long)N_NODES * 16;
            apply_kernel<<<(int)((t2 + 255) / 256), 256, 0, stream>>>(
                agg, batch, Ag, Bg, (float*)d_out);
        }
    }
}

// Round 16
// 137.446 us; speedup vs baseline: 1.4484x; 1.0385x over previous
//
#include <hip/hip_runtime.h>

#define N_NODES 100000
#define N_EDGES 1600000
#define D 64
#define NUM_GRAPHS 64
#define EPS 1e-5f

// ---- bucketed CSR build params ----
#define BSHIFT 8
#define NPB 256
#define NBUCKETS ((N_NODES + NPB - 1) / NPB)      // 391
#define BCAP 6144                                  // expected 4082, +32 sigma
#define A_THREADS 1024
#define A_EPT 4
#define A_CHUNK (A_THREADS * A_EPT)               // 4096
#define NBLK_A ((N_EDGES + A_CHUNK - 1) / A_CHUNK) // 391
#define XB ((N_NODES * 64 / 8 + 255) / 256)       // xcast blocks (3125)

// ---- legacy scan params (fallback path) ----
#define SCAN_T 256
#define SCAN_E 8
#define SCAN_CHUNK (SCAN_T * SCAN_E)
#define NSCAN ((N_NODES + SCAN_CHUNK - 1) / SCAN_CHUNK)

typedef float f32x4 __attribute__((ext_vector_type(4)));
typedef short bf16x8 __attribute__((ext_vector_type(8)));

__device__ __forceinline__ ushort f32_to_bf16_rne(float v) {
    unsigned int bits = __float_as_uint(v);
    return (ushort)((bits + 0x7FFFu + ((bits >> 16) & 1u)) >> 16);
}
__device__ __forceinline__ float bf16lo_to_f32(unsigned int u) {
    return __uint_as_float(u << 16);
}
__device__ __forceinline__ float bf16hi_to_f32(unsigned int u) {
    return __uint_as_float(u & 0xFFFF0000u);
}

// ===========================================================================
// fused: blocks [0,XB) cast x->bf16; blocks [XB,XB+16) init cursors + stats
// ===========================================================================
__global__ __launch_bounds__(256) void xcast_init_kernel(
    const float* __restrict__ x, ushort* __restrict__ xh,
    int* __restrict__ bucket_cur, float* __restrict__ gsum,
    float* __restrict__ gsum2, float* __restrict__ gcnt)
{
    if (blockIdx.x < XB) {
        int i = blockIdx.x * blockDim.x + threadIdx.x;
        if (i >= N_NODES * 64 / 8) return;
        const float4* src = reinterpret_cast<const float4*>(x) + (size_t)i * 2;
        float4 v0 = src[0], v1 = src[1];
        float vf[8] = {v0.x, v0.y, v0.z, v0.w, v1.x, v1.y, v1.z, v1.w};
        union { ushort us[8]; uint4 u4; } o;
        #pragma unroll
        for (int j = 0; j < 8; ++j) o.us[j] = f32_to_bf16_rne(vf[j]);
        reinterpret_cast<uint4*>(xh)[i] = o.u4;
    } else {
        int i = (blockIdx.x - XB) * 256 + threadIdx.x;   // 0..4095
        if (i < NBUCKETS) bucket_cur[i] = i * BCAP;
        if (i < NUM_GRAPHS * 64) { gsum[i] = 0.f; gsum2[i] = 0.f; }
        if (i < 64) gcnt[i] = 0.f;
    }
}

// ===========================================================================
// bin edges into fixed-capacity bucket regions (391 buckets of 256 nodes).
// packed 8B: lo = src | (dst&255)<<17 ; hi = w f32 bits
// ===========================================================================
__global__ __launch_bounds__(A_THREADS) void binA_kernel(
    const int* __restrict__ src_idx, const int* __restrict__ dst_idx,
    const float* __restrict__ ea, int* __restrict__ bucket_cursor,
    unsigned long long* __restrict__ binned)
{
    __shared__ int hist[NBUCKETS];
    __shared__ int lbase[NBUCKETS];
    int tid = threadIdx.x;
    if (tid < NBUCKETS) hist[tid] = 0;
    __syncthreads();

    int base = blockIdx.x * A_CHUNK;
    int srcv[A_EPT], dstv[A_EPT];
    float wv[A_EPT];
    #pragma unroll
    for (int i = 0; i < A_EPT; ++i) {
        int e = base + i * A_THREADS + tid;
        if (e < N_EDGES) {
            srcv[i] = src_idx[e];
            dstv[i] = dst_idx[e];
            wv[i]   = ea[e];
            atomicAdd(&hist[dstv[i] >> BSHIFT], 1);
        } else {
            dstv[i] = -1; srcv[i] = 0; wv[i] = 0.f;
        }
    }
    __syncthreads();
    if (tid < NBUCKETS) lbase[tid] = atomicAdd(&bucket_cursor[tid], hist[tid]);
    __syncthreads();
    if (tid < NBUCKETS) hist[tid] = 0;
    __syncthreads();
    #pragma unroll
    for (int i = 0; i < A_EPT; ++i) {
        if (dstv[i] >= 0) {
            int b = dstv[i] >> BSHIFT;
            int r = atomicAdd(&hist[b], 1);
            unsigned int lo = (unsigned int)(srcv[i] | ((dstv[i] & (NPB - 1)) << 17));
            unsigned long long pv = (unsigned long long)lo |
                ((unsigned long long)__float_as_uint(wv[i]) << 32);
            binned[lbase[b] + r] = pv;
        }
    }
}

// ===========================================================================
// per-bucket counting sort -> offsets2[] (int2 beg,end) + packed 4B csr[]
// 391 blocks; NPB=256 so dcnt scan is a direct 256-thread pass.
// csr entry: src(17b) | w_e8m7(15b)<<17
// ===========================================================================
__global__ __launch_bounds__(256) void binB_kernel(
    const unsigned long long* __restrict__ binned,
    const int* __restrict__ bucket_cur,
    int2* __restrict__ offsets2, unsigned int* __restrict__ csr)
{
    __shared__ int dcnt[NPB];
    __shared__ int doff[NPB];
    __shared__ int psum[256];
    int tid = threadIdx.x;
    int b = blockIdx.x;
    int beg = b * BCAP;
    int n = bucket_cur[b] - beg;

    dcnt[tid] = 0;
    __syncthreads();
    for (int j = tid; j < n; j += 256) {
        unsigned long long pv = binned[beg + j];
        atomicAdd(&dcnt[(((unsigned int)pv) >> 17) & (NPB - 1)], 1);
    }
    __syncthreads();
    psum[tid] = dcnt[tid];
    __syncthreads();
    for (int off = 1; off < 256; off <<= 1) {
        int v = psum[tid];
        int a = (tid >= off) ? psum[tid - off] : 0;
        __syncthreads();
        psum[tid] = v + a;
        __syncthreads();
    }
    int ex = (tid == 0) ? 0 : psum[tid - 1];
    doff[tid] = ex;
    __syncthreads();
    {
        int node = (b << BSHIFT) + tid;
        if (node < N_NODES) {
            int s = beg + doff[tid];
            int e = beg + ((tid + 1 < NPB) ? doff[tid + 1] : n);
            offsets2[node] = make_int2(s, e);
        }
        dcnt[tid] = doff[tid];
    }
    __syncthreads();
    for (int j = tid; j < n; j += 256) {
        unsigned long long pv = binned[beg + j];
        unsigned int lo = (unsigned int)pv;
        unsigned int wbits = (unsigned int)(pv >> 32);
        int dlo = (lo >> 17) & (NPB - 1);
        int r = atomicAdd(&dcnt[dlo], 1);
        unsigned int field = ((wbits + 0x7FFFu + ((wbits >> 16) & 1u)) >> 16) & 0x7FFFu;
        csr[beg + r] = (lo & 0x1FFFFu) | (field << 17);
    }
}

// ===========================================================================
// Gather-aggregate: 4 nodes/wave, 16 lanes/node, 4 dims/lane, 4-deep unroll.
// ===========================================================================
__global__ __launch_bounds__(256) void gatherh4_kernel(
    const ushort* __restrict__ xh, const int2* __restrict__ offsets2,
    const unsigned int* __restrict__ csr, ushort* __restrict__ agg)
{
    int tid = threadIdx.x;
    int wave = tid >> 6, lane = tid & 63;
    int grp = lane >> 4, sl = lane & 15;
    int node = blockIdx.x * 16 + wave * 4 + grp;
    bool ok = (node < N_NODES);
    int2 o2 = ok ? offsets2[node] : make_int2(0, 0);
    int beg = o2.x, end = o2.y;

    float acc[4][4];
    #pragma unroll
    for (int s = 0; s < 4; ++s)
        #pragma unroll
        for (int i = 0; i < 4; ++i) acc[s][i] = 0.f;

    int j = beg;
    for (; j + 3 < end; j += 4) {
        unsigned int e[4];
        #pragma unroll
        for (int u = 0; u < 4; ++u) e[u] = csr[j + u];
        uint2 xv[4];
        #pragma unroll
        for (int u = 0; u < 4; ++u)
            xv[u] = *reinterpret_cast<const uint2*>(
                xh + (size_t)(e[u] & 0x1FFFFu) * 64 + sl * 4);
        #pragma unroll
        for (int u = 0; u < 4; ++u) {
            float w = __uint_as_float((e[u] >> 17) << 16);
            acc[u][0] = fmaf(w, bf16lo_to_f32(xv[u].x & 0xFFFFu), acc[u][0]);
            acc[u][1] = fmaf(w, bf16hi_to_f32(xv[u].x), acc[u][1]);
            acc[u][2] = fmaf(w, bf16lo_to_f32(xv[u].y & 0xFFFFu), acc[u][2]);
            acc[u][3] = fmaf(w, bf16hi_to_f32(xv[u].y), acc[u][3]);
        }
    }
    for (; j < end; ++j) {
        unsigned int e0 = csr[j];
        uint2 x0 = *reinterpret_cast<const uint2*>(
            xh + (size_t)(e0 & 0x1FFFFu) * 64 + sl * 4);
        float w = __uint_as_float((e0 >> 17) << 16);
        acc[0][0] = fmaf(w, bf16lo_to_f32(x0.x & 0xFFFFu), acc[0][0]);
        acc[0][1] = fmaf(w, bf16hi_to_f32(x0.x), acc[0][1]);
        acc[0][2] = fmaf(w, bf16lo_to_f32(x0.y & 0xFFFFu), acc[0][2]);
        acc[0][3] = fmaf(w, bf16hi_to_f32(x0.y), acc[0][3]);
    }
    if (ok) {
        float r0 = (acc[0][0] + acc[1][0]) + (acc[2][0] + acc[3][0]);
        float r1 = (acc[0][1] + acc[1][1]) + (acc[2][1] + acc[3][1]);
        float r2 = (acc[0][2] + acc[1][2]) + (acc[2][2] + acc[3][2]);
        float r3 = (acc[0][3] + acc[1][3]) + (acc[2][3] + acc[3][3]);
        unsigned int lo = (unsigned int)f32_to_bf16_rne(r0)
                        | ((unsigned int)f32_to_bf16_rne(r1) << 16);
        unsigned int hi = (unsigned int)f32_to_bf16_rne(r2)
                        | ((unsigned int)f32_to_bf16_rne(r3) << 16);
        *reinterpret_cast<uint2*>(agg + (size_t)node * 64 + sl * 4) =
            make_uint2(lo, hi);
    }
}

// ===========================================================================
// Dense (MFMA, plain bf16 inputs): h = relu([agg|x] @ [W^T] + b) -> bf16
// ===========================================================================
#define DB 128
__global__ __launch_bounds__(256) void dense_mfma16_kernel(
    const ushort* __restrict__ agg, const ushort* __restrict__ xh,
    ushort* __restrict__ hout,
    const float* __restrict__ W_rel, const float* __restrict__ b_rel,
    const float* __restrict__ W_root)
{
    __shared__ unsigned int Bf[4][4][64][4];   // 16 KB
    int tid = threadIdx.x;

    #pragma unroll
    for (int g = 0; g < 8; ++g) {
        int q = tid * 8 + g;
        int i4   = (q & 1) * 4;
        int lane = (q >> 1) & 63;
        int dt   = (q >> 7) & 3;
        int kt   = (q >> 9) & 3;
        int d = dt * 16 + (lane & 15);
        int k = kt * 32 + (lane >> 4) * 8 + i4;
        const float* Wsrc = (k < 64) ? (W_rel + d * 64 + k)
                                     : (W_root + d * 64 + (k - 64));
        float4 w = *reinterpret_cast<const float4*>(Wsrc);
        unsigned int b0 = f32_to_bf16_rne(w.x);
        unsigned int b1 = f32_to_bf16_rne(w.y);
        unsigned int b2 = f32_to_bf16_rne(w.z);
        unsigned int b3 = f32_to_bf16_rne(w.w);
        int u = i4 >> 1;
        Bf[kt][dt][lane][u]     = b0 | (b1 << 16);
        Bf[kt][dt][lane][u + 1] = b2 | (b3 << 16);
    }
    __syncthreads();

    int wid = tid >> 6, lane = tid & 63;
    int nbase = blockIdx.x * DB + wid * 32;
    int r = lane & 15;
    int k0 = (lane >> 4) * 8;

    f32x4 acc[2][4];
    #pragma unroll
    for (int nt = 0; nt < 2; ++nt)
        #pragma unroll
        for (int dt = 0; dt < 4; ++dt)
            acc[nt][dt] = (f32x4){0.f, 0.f, 0.f, 0.f};

    bf16x8 zf;
    #pragma unroll
    for (int i = 0; i < 8; ++i) zf[i] = 0;

    #pragma unroll 1
    for (int kt = 0; kt < 4; ++kt) {
        bf16x8 bh[4];
        #pragma unroll
        for (int dt = 0; dt < 4; ++dt)
            bh[dt] = *reinterpret_cast<const bf16x8*>(&Bf[kt][dt][lane][0]);
        int kk = kt * 32 + k0;
        #pragma unroll
        for (int nt = 0; nt < 2; ++nt) {
            int node = nbase + nt * 16 + r;
            bool ok = (node < N_NODES);
            const ushort* srcrow = (kk < 64)
                ? (agg + (size_t)node * 64 + kk)
                : (xh + (size_t)node * 64 + (kk - 64));
            bf16x8 a = ok ? *reinterpret_cast<const bf16x8*>(srcrow) : zf;
            #pragma unroll
            for (int dt = 0; dt < 4; ++dt)
                acc[nt][dt] = __builtin_amdgcn_mfma_f32_16x16x32_bf16(a, bh[dt], acc[nt][dt], 0, 0, 0);
        }
    }

    int rowg = (lane >> 4) * 4;
    #pragma unroll
    for (int dt = 0; dt < 4; ++dt) {
        int d = dt * 16 + r;
        float bias = b_rel[d];
        #pragma unroll
        for (int nt = 0; nt < 2; ++nt) {
            #pragma unroll
            for (int reg = 0; reg < 4; ++reg) {
                int node = nbase + nt * 16 + rowg + reg;
                if (node < N_NODES) {
                    float v = fmaxf(acc[nt][dt][reg] + bias, 0.f);
                    hout[(size_t)node * 64 + d] = f32_to_bf16_rne(v);
                }
            }
        }
    }
}

// ===========================================================================
// stats (bf16 h): per-(graph, dim) sum, sum^2, count
// ===========================================================================
#define NPW 32
__global__ __launch_bounds__(256) void stats16_kernel(
    const ushort* __restrict__ h,
    const int* __restrict__ batch,
    float* __restrict__ gsum,
    float* __restrict__ gsum2,
    float* __restrict__ gcnt)
{
    int wave = (int)((blockIdx.x * blockDim.x + threadIdx.x) >> 6);
    int lane = threadIdx.x & 63;
    int base = wave * NPW;
    if (base >= N_NODES) return;
    int end = min(base + NPW, N_NODES);

    int gcur = batch[base];
    float s = 0.f, s2 = 0.f, cnt = 0.f;
    for (int n = base; n < end; ++n) {
        int g = batch[n];
        if (g != gcur) {
            atomicAdd(&gsum[gcur * 64 + lane], s);
            atomicAdd(&gsum2[gcur * 64 + lane], s2);
            if (lane == 0) atomicAdd(&gcnt[gcur], cnt);
            s = 0.f; s2 = 0.f; cnt = 0.f;
            gcur = g;
        }
        float v = __uint_as_float((unsigned int)h[(size_t)n * 64 + lane] << 16);
        s += v;
        s2 = fmaf(v, v, s2);
        cnt += 1.f;
    }
    atomicAdd(&gsum[gcur * 64 + lane], s);
    atomicAdd(&gsum2[gcur * 64 + lane], s2);
    if (lane == 0) atomicAdd(&gcnt[gcur], cnt);
}

// ===========================================================================
// finalize: fold stats into per-(g,d) affine A,B
// ===========================================================================
__global__ __launch_bounds__(256) void finalize_kernel(
    const float* __restrict__ gsum,
    const float* __restrict__ gsum2,
    const float* __restrict__ gcnt,
    const float* __restrict__ gn_w,
    const float* __restrict__ gn_b,
    const float* __restrict__ gn_ms,
    float* __restrict__ Ag,
    float* __restrict__ Bg)
{
    int i = blockIdx.x * blockDim.x + threadIdx.x;
    if (i >= NUM_GRAPHS * 64) return;
    int g = i >> 6, d = i & 63;
    float c = fmaxf(gcnt[g], 1.f);
    float m = gsum[i] / c;
    float q = gsum2[i] / c;
    float s = gn_ms[d];
    float var = q - (2.f * s - s * s) * m * m;
    float inv = rsqrtf(fmaxf(var, 0.f) + EPS);
    float A = gn_w[d] * inv;
    Ag[i] = A;
    Bg[i] = gn_b[d] - A * s * m;
}

// ===========================================================================
// apply (bf16 h): out[n][d] = A[g][d]*h[n][d] + B[g][d]; 8 dims/thread
// ===========================================================================
__global__ __launch_bounds__(256) void apply16_kernel(
    const ushort* __restrict__ h,
    const int* __restrict__ batch,
    const float* __restrict__ Ag,
    const float* __restrict__ Bg,
    float* __restrict__ out)
{
    int i = blockIdx.x * blockDim.x + threadIdx.x;
    if (i >= N_NODES * 8) return;
    int n = i >> 3;
    int q = i & 7;
    int g = batch[n];
    union { uint4 u4; ushort us[8]; } hv;
    hv.u4 = *reinterpret_cast<const uint4*>(h + (size_t)n * 64 + q * 8);
    const float4* Av = reinterpret_cast<const float4*>(Ag + g * 64 + q * 8);
    const float4* Bv = reinterpret_cast<const float4*>(Bg + g * 64 + q * 8);
    float4 A0 = Av[0], A1 = Av[1];
    float4 B0 = Bv[0], B1 = Bv[1];
    float Af[8] = {A0.x, A0.y, A0.z, A0.w, A1.x, A1.y, A1.z, A1.w};
    float Bf_[8] = {B0.x, B0.y, B0.z, B0.w, B1.x, B1.y, B1.z, B1.w};
    float4 o0, o1;
    float of[8];
    #pragma unroll
    for (int j = 0; j < 8; ++j) {
        float v = __uint_as_float((unsigned int)hv.us[j] << 16);
        of[j] = fmaf(Af[j], v, Bf_[j]);
    }
    o0.x = of[0]; o0.y = of[1]; o0.z = of[2]; o0.w = of[3];
    o1.x = of[4]; o1.y = of[5]; o1.z = of[6]; o1.w = of[7];
    float4* op = reinterpret_cast<float4*>(out + (size_t)n * 64 + q * 8);
    op[0] = o0;
    op[1] = o1;
}

// ===========================================================================
// LEGACY PATH (fallback tiers, f32 h)
// ===========================================================================
__global__ __launch_bounds__(256) void hist_kernel(
    const int* __restrict__ dst_idx, int* __restrict__ deg)
{
    int e = blockIdx.x * blockDim.x + threadIdx.x;
    if (e >= N_EDGES) return;
    atomicAdd(&deg[dst_idx[e]], 1);
}

__global__ __launch_bounds__(SCAN_T) void scan1_kernel(
    const int* __restrict__ deg, int* __restrict__ offsets,
    int* __restrict__ blocksum)
{
    __shared__ int lds[SCAN_T];
    int b = blockIdx.x, t = threadIdx.x;
    int base = b * SCAN_CHUNK + t * SCAN_E;
    int v[SCAN_E];
    int s = 0;
    #pragma unroll
    for (int i = 0; i < SCAN_E; ++i) {
        v[i] = (base + i < N_NODES) ? deg[base + i] : 0;
        s += v[i];
    }
    lds[t] = s;
    __syncthreads();
    for (int off = 1; off < SCAN_T; off <<= 1) {
        int val = lds[t];
        int add = (t >= off) ? lds[t - off] : 0;
        __syncthreads();
        lds[t] = val + add;
        __syncthreads();
    }
    if (t == SCAN_T - 1) blocksum[b] = lds[SCAN_T - 1];
    int run = (t == 0) ? 0 : lds[t - 1];
    #pragma unroll
    for (int i = 0; i < SCAN_E; ++i) {
        if (base + i < N_NODES) offsets[base + i] = run;
        run += v[i];
    }
}

__global__ __launch_bounds__(64) void scan2_kernel(
    const int* __restrict__ blocksum, int* __restrict__ blockoff)
{
    __shared__ int lds[64];
    int t = threadIdx.x;
    lds[t] = (t < NSCAN) ? blocksum[t] : 0;
    __syncthreads();
    for (int off = 1; off < 64; off <<= 1) {
        int val = lds[t];
        int add = (t >= off) ? lds[t - off] : 0;
        __syncthreads();
        lds[t] = val + add;
        __syncthreads();
    }
    if (t < NSCAN) blockoff[t] = (t == 0) ? 0 : lds[t - 1];
}

__global__ __launch_bounds__(256) void scan3_kernel(
    int* __restrict__ offsets, const int* __restrict__ blockoff,
    int* __restrict__ cursor)
{
    int i = blockIdx.x * blockDim.x + threadIdx.x;
    if (i < N_NODES) {
        int v = offsets[i] + blockoff[i / SCAN_CHUNK];
        offsets[i] = v;
        cursor[i] = v;
    }
    if (i == 0) offsets[N_NODES] = N_EDGES;
}

__global__ __launch_bounds__(256) void fill_kernel(
    const int* __restrict__ src_idx, const int* __restrict__ dst_idx,
    const float* __restrict__ ea, int* __restrict__ cursor,
    int2* __restrict__ csr)
{
    int e = blockIdx.x * blockDim.x + threadIdx.x;
    if (e >= N_EDGES) return;
    int s = src_idx[e];
    int d = dst_idx[e];
    float w = ea[e];
    int pos = atomicAdd(&cursor[d], 1);
    csr[pos] = make_int2(s, __float_as_int(w));
}

__global__ __launch_bounds__(256) void gather_kernel(
    const float* __restrict__ x, const int* __restrict__ offsets,
    const int2* __restrict__ csr, float* __restrict__ agg)
{
    int wid = (int)((blockIdx.x * blockDim.x + threadIdx.x) >> 6);
    if (wid >= N_NODES) return;
    int lane = threadIdx.x & 63;
    int beg = __builtin_amdgcn_readfirstlane(offsets[wid]);
    int end = __builtin_amdgcn_readfirstlane(offsets[wid + 1]);
    float acc0 = 0.f, acc1 = 0.f;
    int j = beg;
    for (; j + 1 < end; j += 2) {
        int2 a = csr[j];
        int2 b = csr[j + 1];
        acc0 = fmaf(__int_as_float(a.y), x[(size_t)a.x * 64 + lane], acc0);
        acc1 = fmaf(__int_as_float(b.y), x[(size_t)b.x * 64 + lane], acc1);
    }
    if (j < end) {
        int2 a = csr[j];
        acc0 = fmaf(__int_as_float(a.y), x[(size_t)a.x * 64 + lane], acc0);
    }
    agg[(size_t)wid * 64 + lane] = acc0 + acc1;
}

__global__ __launch_bounds__(256) void scatter_kernel(
    const float* __restrict__ x,
    const int* __restrict__ src_idx,
    const int* __restrict__ dst_idx,
    const float* __restrict__ ea,
    float* __restrict__ agg)
{
    long long gid = (long long)blockIdx.x * blockDim.x + threadIdx.x;
    if (gid >= (long long)N_EDGES * 16) return;
    int e = (int)(gid >> 4);
    int q = (int)(gid & 15);
    int s = src_idx[e];
    int d = dst_idx[e];
    float w = ea[e];
    float4 v = reinterpret_cast<const float4*>(x)[(size_t)s * 16 + q];
    float* out = agg + (size_t)d * 64 + q * 4;
    atomicAdd(out + 0, w * v.x);
    atomicAdd(out + 1, w * v.y);
    atomicAdd(out + 2, w * v.z);
    atomicAdd(out + 3, w * v.w);
}

// fallback dense (f32 agg/x inputs, in-place, split-precision) — tiers 2/3
__global__ __launch_bounds__(256) void dense_mfma_kernel(
    float* __restrict__ aggh,
    const float* __restrict__ x,
    const float* __restrict__ W_rel,
    const float* __restrict__ b_rel,
    const float* __restrict__ W_root)
{
    __shared__ unsigned int Bf[2][4][4][64][4];
    int tid = threadIdx.x;
    #pragma unroll
    for (int g = 0; g < 8; ++g) {
        int q = tid * 8 + g;
        int i4   = (q & 1) * 4;
        int lane = (q >> 1) & 63;
        int dt   = (q >> 7) & 3;
        int kt   = (q >> 9) & 3;
        int d = dt * 16 + (lane & 15);
        int k = kt * 32 + (lane >> 4) * 8 + i4;
        const float* Wsrc = (k < 64) ? (W_rel + d * 64 + k)
                                     : (W_root + d * 64 + (k - 64));
        float4 w = *reinterpret_cast<const float4*>(Wsrc);
        float wf[4] = {w.x, w.y, w.z, w.w};
        unsigned int hi[4], lo[4];
        #pragma unroll
        for (int j = 0; j < 4; ++j) {
            unsigned int bits = __float_as_uint(wf[j]);
            hi[j] = bits >> 16;
            float resid = wf[j] - __uint_as_float(bits & 0xFFFF0000u);
            lo[j] = __float_as_uint(resid) >> 16;
        }
        int u = i4 >> 1;
        Bf[0][kt][dt][lane][u]     = hi[0] | (hi[1] << 16);
        Bf[0][kt][dt][lane][u + 1] = hi[2] | (hi[3] << 16);
        Bf[1][kt][dt][lane][u]     = lo[0] | (lo[1] << 16);
        Bf[1][kt][dt][lane][u + 1] = lo[2] | (lo[3] << 16);
    }
    __syncthreads();

    int wid = tid >> 6, lane = tid & 63;
    int nbase = blockIdx.x * DB + wid * 32;
    int r = lane & 15;
    int k0 = (lane >> 4) * 8;

    f32x4 acc[2][4];
    #pragma unroll
    for (int nt = 0; nt < 2; ++nt)
        #pragma unroll
        for (int dt = 0; dt < 4; ++dt)
            acc[nt][dt] = (f32x4){0.f, 0.f, 0.f, 0.f};

    #pragma unroll 1
    for (int kt = 0; kt < 4; ++kt) {
        bf16x8 bh[4], bl[4];
        #pragma unroll
        for (int dt = 0; dt < 4; ++dt) {
            bh[dt] = *reinterpret_cast<const bf16x8*>(&Bf[0][kt][dt][lane][0]);
            bl[dt] = *reinterpret_cast<const bf16x8*>(&Bf[1][kt][dt][lane][0]);
        }
        int kk = kt * 32 + k0;
        #pragma unroll
        for (int nt = 0; nt < 2; ++nt) {
            int node = nbase + nt * 16 + r;
            float av[8];
            if (node < N_NODES) {
                const float* srcrow = (kk < 64)
                    ? (aggh + (size_t)node * 64 + kk)
                    : (x + (size_t)node * 64 + (kk - 64));
                float4 v0 = reinterpret_cast<const float4*>(srcrow)[0];
                float4 v1 = reinterpret_cast<const float4*>(srcrow)[1];
                av[0] = v0.x; av[1] = v0.y; av[2] = v0.z; av[3] = v0.w;
                av[4] = v1.x; av[5] = v1.y; av[6] = v1.z; av[7] = v1.w;
            } else {
                #pragma unroll
                for (int i = 0; i < 8; ++i) av[i] = 0.f;
            }
            bf16x8 ah, al;
            #pragma unroll
            for (int i = 0; i < 8; ++i) {
                unsigned int bits = __float_as_uint(av[i]);
                ah[i] = (short)(bits >> 16);
                float resid = av[i] - __uint_as_float(bits & 0xFFFF0000u);
                al[i] = (short)(__float_as_uint(resid) >> 16);
            }
            #pragma unroll
            for (int dt = 0; dt < 4; ++dt) {
                acc[nt][dt] = __builtin_amdgcn_mfma_f32_16x16x32_bf16(ah, bh[dt], acc[nt][dt], 0, 0, 0);
                acc[nt][dt] = __builtin_amdgcn_mfma_f32_16x16x32_bf16(al, bh[dt], acc[nt][dt], 0, 0, 0);
                acc[nt][dt] = __builtin_amdgcn_mfma_f32_16x16x32_bf16(ah, bl[dt], acc[nt][dt], 0, 0, 0);
            }
        }
    }

    int rowg = (lane >> 4) * 4;
    #pragma unroll
    for (int dt = 0; dt < 4; ++dt) {
        int d = dt * 16 + r;
        float bias = b_rel[d];
        #pragma unroll
        for (int nt = 0; nt < 2; ++nt) {
            #pragma unroll
            for (int reg = 0; reg < 4; ++reg) {
                int node = nbase + nt * 16 + rowg + reg;
                if (node < N_NODES) {
                    float v = fmaxf(acc[nt][dt][reg] + bias, 0.f);
                    aggh[(size_t)node * 64 + d] = v;
                }
            }
        }
    }
}

#define NPW2 32
__global__ __launch_bounds__(256) void stats_kernel(
    const float* __restrict__ h,
    const int* __restrict__ batch,
    float* __restrict__ gsum,
    float* __restrict__ gsum2,
    float* __restrict__ gcnt)
{
    int wave = (int)((blockIdx.x * blockDim.x + threadIdx.x) >> 6);
    int lane = threadIdx.x & 63;
    int base = wave * NPW2;
    if (base >= N_NODES) return;
    int end = min(base + NPW2, N_NODES);

    int gcur = batch[base];
    float s = 0.f, s2 = 0.f, cnt = 0.f;
    for (int n = base; n < end; ++n) {
        int g = batch[n];
        if (g != gcur) {
            atomicAdd(&gsum[gcur * 64 + lane], s);
            atomicAdd(&gsum2[gcur * 64 + lane], s2);
            if (lane == 0) atomicAdd(&gcnt[gcur], cnt);
            s = 0.f; s2 = 0.f; cnt = 0.f;
            gcur = g;
        }
        float v = h[(size_t)n * 64 + lane];
        s += v;
        s2 = fmaf(v, v, s2);
        cnt += 1.f;
    }
    atomicAdd(&gsum[gcur * 64 + lane], s);
    atomicAdd(&gsum2[gcur * 64 + lane], s2);
    if (lane == 0) atomicAdd(&gcnt[gcur], cnt);
}

__global__ __launch_bounds__(256) void apply_kernel(
    const float* __restrict__ h,
    const int* __restrict__ batch,
    const float* __restrict__ Ag,
    const float* __restrict__ Bg,
    float* __restrict__ out)
{
    long long gid = (long long)blockIdx.x * blockDim.x + threadIdx.x;
    if (gid >= (long long)N_NODES * 16) return;
    int n = (int)(gid >> 4);
    int q = (int)(gid & 15);
    int g = batch[n];
    float4 hv = reinterpret_cast<const float4*>(h)[gid];
    float4 A = reinterpret_cast<const float4*>(Ag)[g * 16 + q];
    float4 B = reinterpret_cast<const float4*>(Bg)[g * 16 + q];
    float4 o;
    o.x = fmaf(A.x, hv.x, B.x);
    o.y = fmaf(A.y, hv.y, B.y);
    o.z = fmaf(A.z, hv.z, B.z);
    o.w = fmaf(A.w, hv.w, B.w);
    reinterpret_cast<float4*>(out)[gid] = o;
}

// ===========================================================================
extern "C" void kernel_launch(void* const* d_in, const int* in_sizes, int n_in,
                              void* d_out, int out_size, void* d_ws, size_t ws_size,
                              hipStream_t stream)
{
    const float* x      = (const float*)d_in[0];
    const int*   ei     = (const int*)d_in[1];
    const float* ea     = (const float*)d_in[2];
    const int*   batch  = (const int*)d_in[3];
    const float* W_rel  = (const float*)d_in[4];
    const float* b_rel  = (const float*)d_in[5];
    const float* W_root = (const float*)d_in[6];
    const float* gn_w   = (const float*)d_in[7];
    const float* gn_b   = (const float*)d_in[8];
    const float* gn_ms  = (const float*)d_in[9];
    const int* src_idx = ei;
    const int* dst_idx = ei + N_EDGES;

    char* wsp = (char*)d_ws;

    // ---------------- tier-1 layout (fixed-capacity buckets) ----------------
    int*   bucket_cur  = (int*)wsp;                                   // 512 (NBUCKETS=391)
    float* gsumN       = (float*)(bucket_cur + 512);                  // G*64
    float* gsum2N      = gsumN + NUM_GRAPHS * 64;                     // G*64
    float* gcntN       = gsum2N + NUM_GRAPHS * 64;                    // 64
    int2*  offsets2    = (int2*)(gcntN + 64);                         // N int2
    size_t regA_off    = (((size_t)((char*)(offsets2 + N_NODES) - wsp)) + 15) & ~(size_t)15;
    size_t binned_sz   = (size_t)NBUCKETS * BCAP * 8;
    size_t hbuf_sz     = (size_t)N_NODES * 64 * 2;
    size_t regA_sz     = (binned_sz > hbuf_sz ? binned_sz : hbuf_sz);
    unsigned long long* binned = (unsigned long long*)(wsp + regA_off);
    ushort* hbuf16     = (ushort*)(wsp + regA_off);
    unsigned int* csrN = (unsigned int*)(wsp + regA_off + regA_sz);   // NBUCKETS*BCAP*4B
    ushort* aggN       = (ushort*)((char*)csrN + (size_t)NBUCKETS * BCAP * 4);
    float*  AgN        = (float*)(aggN + (size_t)N_NODES * 64);
    float*  BgN        = AgN + NUM_GRAPHS * 64;
    ushort* xh         = (ushort*)(BgN + NUM_GRAPHS * 64);
    size_t reqN        = (size_t)((char*)(xh + (size_t)N_NODES * 64) - wsp);

    // ---------------- legacy layouts (tiers 2/3) ----------------
    int*   degL     = (int*)wsp;
    float* gsumL    = (float*)(degL + N_NODES);
    float* gsum2L   = gsumL + NUM_GRAPHS * 64;
    float* gcntL    = gsum2L + NUM_GRAPHS * 64;
    size_t zeroL    = ((size_t)N_NODES + 2 * NUM_GRAPHS * 64 + 64) * 4;
    int*   offsetsL = (int*)(gcntL + 64);
    int*   blocksum = offsetsL + N_NODES + 1;
    int*   blockoff = blocksum + 64;
    int*   cursorL  = blockoff + 64;
    size_t csrL_off = (((size_t)((char*)(cursorL + N_NODES) - wsp)) + 15) & ~(size_t)15;
    int2*  csrL     = (int2*)(wsp + csrL_off);
    float* aggL     = (float*)(csrL + N_EDGES);
    float* AgL      = aggL + (size_t)N_NODES * 64;
    float* BgL      = AgL + NUM_GRAPHS * 64;
    size_t reqL     = (size_t)((char*)(BgL + NUM_GRAPHS * 64) - wsp);

    if (ws_size >= reqN) {
        // ---------- tier 1 (8 launches) ----------
        xcast_init_kernel<<<XB + 16, 256, 0, stream>>>(
            x, xh, bucket_cur, gsumN, gsum2N, gcntN);
        binA_kernel<<<NBLK_A, A_THREADS, 0, stream>>>(src_idx, dst_idx, ea, bucket_cur, binned);
        binB_kernel<<<NBUCKETS, 256, 0, stream>>>(binned, bucket_cur, offsets2, csrN);
        gatherh4_kernel<<<(N_NODES + 15) / 16, 256, 0, stream>>>(xh, offsets2, csrN, aggN);
        dense_mfma16_kernel<<<(N_NODES + DB - 1) / DB, 256, 0, stream>>>(
            aggN, xh, hbuf16, W_rel, b_rel, W_root);
        {
            int waves = (N_NODES + NPW - 1) / NPW;
            stats16_kernel<<<(waves + 3) / 4, 256, 0, stream>>>(hbuf16, batch, gsumN, gsum2N, gcntN);
        }
        finalize_kernel<<<(NUM_GRAPHS * 64 + 255) / 256, 256, 0, stream>>>(
            gsumN, gsum2N, gcntN, gn_w, gn_b, gn_ms, AgN, BgN);
        apply16_kernel<<<(N_NODES * 8 + 255) / 256, 256, 0, stream>>>(
            hbuf16, batch, AgN, BgN, (float*)d_out);
    } else if (ws_size >= reqL) {
        // ---------- tier 2: legacy CSR (f32) ----------
        hipMemsetAsync(d_ws, 0, zeroL, stream);
        hist_kernel<<<(N_EDGES + 255) / 256, 256, 0, stream>>>(dst_idx, degL);
        scan1_kernel<<<NSCAN, SCAN_T, 0, stream>>>(degL, offsetsL, blocksum);
        scan2_kernel<<<1, 64, 0, stream>>>(blocksum, blockoff);
        scan3_kernel<<<(N_NODES + 255) / 256, 256, 0, stream>>>(offsetsL, blockoff, cursorL);
        fill_kernel<<<(N_EDGES + 255) / 256, 256, 0, stream>>>(src_idx, dst_idx, ea, cursorL, csrL);
        gather_kernel<<<(N_NODES + 3) / 4, 256, 0, stream>>>(x, offsetsL, csrL, aggL);
        dense_mfma_kernel<<<(N_NODES + DB - 1) / DB, 256, 0, stream>>>(
            aggL, x, W_rel, b_rel, W_root);
        {
            int waves = (N_NODES + NPW2 - 1) / NPW2;
            stats_kernel<<<(waves + 3) / 4, 256, 0, stream>>>(aggL, batch, gsumL, gsum2L, gcntL);
        }
        finalize_kernel<<<(NUM_GRAPHS * 64 + 255) / 256, 256, 0, stream>>>(
            gsumL, gsum2L, gcntL, gn_w, gn_b, gn_ms, AgL, BgL);
        {
            long long total = (long long)N_NODES * 16;
            apply_kernel<<<(int)((total + 255) / 256), 256, 0, stream>>>(
                aggL, batch, AgL, BgL, (float*)d_out);
        }
    } else {
        // ---------- tier 3: atomic scatter ----------
        float* agg = (float*)(gcntL + 64);
        float* Ag  = agg + (size_t)N_NODES * 64;
        float* Bg  = Ag + NUM_GRAPHS * 64;
        size_t zb = zeroL + (size_t)N_NODES * 64 * 4;
        hipMemsetAsync(d_ws, 0, zb, stream);
        long long total = (long long)N_EDGES * 16;
        scatter_kernel<<<(int)((total + 255) / 256), 256, 0, stream>>>(
            x, src_idx, dst_idx, ea, agg);
        dense_mfma_kernel<<<(N_NODES + DB - 1) / DB, 256, 0, stream>>>(
            agg, x, W_rel, b_rel, W_root);
        {
            int waves = (N_NODES + NPW2 - 1) / NPW2;
            stats_kernel<<<(waves + 3) / 4, 256, 0, stream>>>(agg, batch, gsumL, gsum2L, gcntL);
        }
        finalize_kernel<<<(NUM_GRAPHS * 64 + 255) / 256, 256, 0, stream>>>(
            gsumL, gsum2L, gcntL, gn_w, gn_b, gn_ms, Ag, Bg);
        {
            long long t2 = (long long)N_NODES * 16;
            apply_kernel<<<(int)((t2 + 255) / 256), 256, 0, stream>>>(
                agg, batch, Ag, Bg, (float*)d_out);
        }
    }
}